// Round 1
// 490.745 us; speedup vs baseline: 1.0356x; 1.0356x over previous
//
#include <hip/hip_runtime.h>
#include <hip/hip_bf16.h>
#include <math.h>

#define B_ROWS 65536
#define D_DIM 256
#define C_DIM 128
#define H_DIM 1024

typedef __bf16 bf16x8 __attribute__((ext_vector_type(8)));
typedef float f32x4 __attribute__((ext_vector_type(4)));
typedef short short8 __attribute__((ext_vector_type(8)));

__device__ __forceinline__ unsigned short f2bf(float f) {
    unsigned int u = __float_as_uint(f);
    u += 0x7fffu + ((u >> 16) & 1u);
    return (unsigned short)(u >> 16);
}

__device__ __forceinline__ void gl2lds16(const void* g, void* l) {
    __builtin_amdgcn_global_load_lds(
        (const __attribute__((address_space(1))) unsigned int*)g,
        (__attribute__((address_space(3))) unsigned int*)l, 16, 0, 0);
}

// XCD-aware swizzle: all 8 N-tiles of one M-tile land on the same XCD.
__device__ __forceinline__ void swizzle_mn(int id, int mtiles, int& m, int& n) {
    if ((mtiles & 7) == 0) {
        int g = id >> 6, r = id & 63;
        m = g * 8 + (r & 7);
        n = r >> 3;
    } else {
        m = id >> 3;
        n = id & 7;
    }
}

// dst[n*R + k] = bf16(src[k*C + n]); src is R x C row-major, dst N x K
__global__ void transpose_bf16(const float* __restrict__ src, short* __restrict__ dst,
                               int R, int C, int total) {
    int tid = blockIdx.x * 256 + threadIdx.x;
    if (tid >= total) return;
    int per = R >> 3;
    int n = tid / per;
    int k0 = (tid - n * per) << 3;
    short8 o;
#pragma unroll
    for (int j = 0; j < 8; ++j) o[j] = (short)f2bf(src[(size_t)(k0 + j) * C + n]);
    *(short8*)&dst[(size_t)n * R + k0] = o;
}

__global__ void prep_b3(const float* __restrict__ bs, const float* __restrict__ bt,
                        float* __restrict__ b3) {
    int i = threadIdx.x;
    b3[i] = (i < 128) ? bs[i] : bt[i - 128];
}

// GEMM1 fused: A[m][k] = k<128 ? x[m][2k] : cond[m][k-128], B = W1T (1024 x 256).
// H1 = relu(A@W1 + b1) bf16.
__global__ __launch_bounds__(256) void gemm1_fused(
    const float* __restrict__ x, const float* __restrict__ cond,
    const short* __restrict__ Bw, const float* __restrict__ bias,
    unsigned short* __restrict__ H1, int mtiles) {
    constexpr int BK = 64, K = 256, N = 1024;
    __shared__ __align__(16) short As[128 * BK];
    __shared__ __align__(16) short Bs[128 * BK];
    const int tid = threadIdx.x;
    const int lane = tid & 63;
    const int wave = tid >> 6;
    int mt, nt;
    swizzle_mn(blockIdx.x, mtiles, mt, nt);
    const int tm = mt * 128, tn = nt * 128;
    const int mo = (wave >> 1) * 64;
    const int no = (wave & 1) * 64;

    f32x4 acc[4][4];
#pragma unroll
    for (int i = 0; i < 4; ++i)
#pragma unroll
        for (int j = 0; j < 4; ++j) acc[i][j] = f32x4{0.f, 0.f, 0.f, 0.f};

    const int srow = lane >> 3;
    const int skb = (lane & 7) ^ srow;

#pragma unroll
    for (int kc = 0; kc < K; kc += BK) {
        __syncthreads();
#pragma unroll
        for (int i = 0; i < 4; ++i) {
            int c = wave * 4 + i;
            int row = c * 8 + srow;
            int kcol = kc + skb * 8;
            float v[8];
            if (kc < 128) {
                const float4* p = (const float4*)(x + (size_t)(tm + row) * 256 + 2 * kcol);
                float4 a = p[0], b = p[1], cc = p[2], d = p[3];
                v[0]=a.x; v[1]=a.z; v[2]=b.x; v[3]=b.z; v[4]=cc.x; v[5]=cc.z; v[6]=d.x; v[7]=d.z;
            } else {
                const float4* p = (const float4*)(cond + (size_t)(tm + row) * 128 + (kcol - 128));
                float4 a = p[0], b = p[1];
                v[0]=a.x; v[1]=a.y; v[2]=a.z; v[3]=a.w; v[4]=b.x; v[5]=b.y; v[6]=b.z; v[7]=b.w;
            }
            short8 o;
#pragma unroll
            for (int j = 0; j < 8; ++j) o[j] = (short)f2bf(v[j]);
            *(short8*)&As[c * 512 + lane * 8] = o;
            gl2lds16(Bw + (size_t)(tn + row) * K + kc + skb * 8, &Bs[c * 512]);
        }
        __syncthreads();
#pragma unroll
        for (int kk = 0; kk < 2; ++kk) {
            bf16x8 af[4], bfr[4];
            int kb = kk * 4 + (lane >> 4);
#pragma unroll
            for (int t = 0; t < 4; ++t) {
                int r = mo + t * 16 + (lane & 15);
                af[t] = *(const bf16x8*)&As[r * BK + ((kb ^ (r & 7)) << 3)];
                int n = no + t * 16 + (lane & 15);
                bfr[t] = *(const bf16x8*)&Bs[n * BK + ((kb ^ (n & 7)) << 3)];
            }
#pragma unroll
            for (int i = 0; i < 4; ++i)
#pragma unroll
                for (int j = 0; j < 4; ++j)
                    acc[i][j] = __builtin_amdgcn_mfma_f32_16x16x32_bf16(
                        af[i], bfr[j], acc[i][j], 0, 0, 0);
        }
    }

#pragma unroll
    for (int j = 0; j < 4; ++j) {
        int col = tn + no + j * 16 + (lane & 15);
        float bb = bias[col];
#pragma unroll
        for (int i = 0; i < 4; ++i) {
            int row0 = tm + mo + i * 16 + ((lane >> 4) << 2);
            f32x4 v = acc[i][j];
#pragma unroll
            for (int rr = 0; rr < 4; ++rr)
                H1[(size_t)(row0 + rr) * N + col] = f2bf(fmaxf(v[rr] + bb, 0.f));
        }
    }
}

// Fallback GEMM2 (old 128x128 structure), only used if RP % 256 != 0.
__global__ __launch_bounds__(256) void gemm_tn(
    const short* __restrict__ A, const short* __restrict__ Bw,
    const float* __restrict__ bias, unsigned short* __restrict__ Cout,
    int mtiles, int N, int K) {
    constexpr int BK = 64;
    __shared__ __align__(16) short As[128 * BK];
    __shared__ __align__(16) short Bs[128 * BK];
    const int tid = threadIdx.x;
    const int lane = tid & 63;
    const int wave = tid >> 6;
    int mt, nt;
    swizzle_mn(blockIdx.x, mtiles, mt, nt);
    const int tm = mt * 128, tn = nt * 128;
    const int mo = (wave >> 1) * 64;
    const int no = (wave & 1) * 64;

    f32x4 acc[4][4];
#pragma unroll
    for (int i = 0; i < 4; ++i)
#pragma unroll
        for (int j = 0; j < 4; ++j) acc[i][j] = f32x4{0.f, 0.f, 0.f, 0.f};

    const int srow = lane >> 3;
    const int skb = (lane & 7) ^ srow;

    for (int kc = 0; kc < K; kc += BK) {
        __syncthreads();
#pragma unroll
        for (int i = 0; i < 4; ++i) {
            int c = wave * 4 + i;
            int row = c * 8 + srow;
            gl2lds16(A + (size_t)(tm + row) * K + kc + skb * 8, &As[c * 512]);
            gl2lds16(Bw + (size_t)(tn + row) * K + kc + skb * 8, &Bs[c * 512]);
        }
        __syncthreads();
#pragma unroll
        for (int kk = 0; kk < 2; ++kk) {
            bf16x8 af[4], bfr[4];
            int kb = kk * 4 + (lane >> 4);
#pragma unroll
            for (int t = 0; t < 4; ++t) {
                int r = mo + t * 16 + (lane & 15);
                af[t] = *(const bf16x8*)&As[r * BK + ((kb ^ (r & 7)) << 3)];
                int n = no + t * 16 + (lane & 15);
                bfr[t] = *(const bf16x8*)&Bs[n * BK + ((kb ^ (n & 7)) << 3)];
            }
#pragma unroll
            for (int i = 0; i < 4; ++i)
#pragma unroll
                for (int j = 0; j < 4; ++j)
                    acc[i][j] = __builtin_amdgcn_mfma_f32_16x16x32_bf16(
                        af[i], bfr[j], acc[i][j], 0, 0, 0);
        }
    }

#pragma unroll
    for (int j = 0; j < 4; ++j) {
        int col = tn + no + j * 16 + (lane & 15);
        float bb = bias[col];
#pragma unroll
        for (int i = 0; i < 4; ++i) {
            int row0 = tm + mo + i * 16 + ((lane >> 4) << 2);
            f32x4 v = acc[i][j];
#pragma unroll
            for (int rr = 0; rr < 4; ++rr)
                Cout[(size_t)(row0 + rr) * N + col] = f2bf(fmaxf(v[rr] + bb, 0.f));
        }
    }
}

// ===========================================================================
// GEMM2, 256x256 tile, BK=64, 8 waves (2M x 4N), 8-phase schedule with
// counted vmcnt (T2+T3+T4+T5). A = H1 (M x 1024 bf16), B = W2T (1024 x 1024
// bf16, N-major), C = relu(A@B^T + bias) bf16.
//
// LDS: double-buffered A(256x64) + B(256x64) = 4 x 32 KB = 128 KB.
// Chunk = 8 rows x 64 cols staged by one wave-wide global_load_lds pair;
// XOR swizzle: lane l of chunk c loads global row c*8+(l>>3), k-block
// (l&7)^(l>>3); read of (row r, kblock kb) at r*64 + ((kb^(r&7))<<3).
//
// Window w (4 phases) computes K-tile w from buf[w&1]:
//   p0: ds_read B frags (8xb128) + A mfrag 0,1 (4xb128); stage U3(w+1)->other
//   p1: A mfrag 2,3; stage U0(w+2)->current   (B region: freed at p0)
//   p2: A mfrag 4,5; stage U1(w+2)->current   (B region)
//   p3: A mfrag 6,7; stage U2(w+2)->current   (A rows 0-63/128-191: freed p0/p1)
//        + vmcnt(6) boundary (vmcnt(0) at tail where stage guards skip)
// Stage units (16 chunks = 2 loads/thread each):
//   U0 = B chunks 0-15, U1 = B chunks 16-31,
//   U2 = A chunks {0-7,16-23} (rows 0-63,128-191),
//   U3 = A chunks {8-15,24-31} (rows 64-127,192-255).
// vmcnt(6) at each window boundary leaves exactly the 3 most recent units
// (p1-p3 stages) in flight; everything older has landed => tile w+1 complete.
// ===========================================================================
__global__ __launch_bounds__(512, 2) void gemm2_8ph(
    const short* __restrict__ A, const short* __restrict__ Bw,
    const float* __restrict__ bias, unsigned short* __restrict__ Cout) {
    constexpr int K = 1024, N = 1024, NT = 16;  // 16 K-tiles of 64
    __shared__ __align__(16) short As0[256 * 64];
    __shared__ __align__(16) short Bs0[256 * 64];
    __shared__ __align__(16) short As1[256 * 64];
    __shared__ __align__(16) short Bs1[256 * 64];

    const int tid = threadIdx.x;
    const int lane = tid & 63;
    const int wave = tid >> 6;      // 0..7
    const int wm = wave >> 2;       // 0..1  -> 128-row half
    const int wn = wave & 3;        // 0..3  -> 64-col quarter
    const int l15 = lane & 15;
    const int quad = lane >> 4;
    const int srow = lane >> 3;
    const int skb8 = ((lane & 7) ^ srow) << 3;

    // bijective XCD swizzle
    const int id = blockIdx.x, nwg = gridDim.x;
    const int xcd = id & 7, lid = id >> 3;
    const int q = nwg >> 3, r = nwg & 7;
    const int wgid = (xcd < r ? xcd * (q + 1) : r * (q + 1) + (xcd - r) * q) + lid;
    const int mt = wgid >> 2, nt = wgid & 3;    // 4 n-tiles (N=1024)
    const size_t Abase = (size_t)(mt * 256) * K;
    const size_t Bbase = (size_t)(nt * 256) * K;

    f32x4 acc[8][4];
#pragma unroll
    for (int m = 0; m < 8; ++m)
#pragma unroll
        for (int n = 0; n < 4; ++n) acc[m][n] = f32x4{0.f, 0.f, 0.f, 0.f};

    short *Ac = As0, *Bc = Bs0, *An = As1, *Bn = Bs1;

    auto stage2 = [&](short* lds, const short* g, size_t rowbase, int kc, int c0, int c1) {
        gl2lds16(g + rowbase + (size_t)(c0 * 8 + srow) * K + kc + skb8, &lds[c0 * 512]);
        gl2lds16(g + rowbase + (size_t)(c1 * 8 + srow) * K + kc + skb8, &lds[c1 * 512]);
    };
    auto stageU = [&](int u, short* Ab, short* Bb, int kc) {
        if (u == 0)      stage2(Bb, Bw, Bbase, kc, wave * 2, wave * 2 + 1);
        else if (u == 1) stage2(Bb, Bw, Bbase, kc, 16 + wave * 2, 17 + wave * 2);
        else if (u == 2) stage2(Ab, A, Abase, kc, wave, 16 + wave);
        else             stage2(Ab, A, Abase, kc, 8 + wave, 24 + wave);
    };

    // ---- prologue: tile0 complete -> buf0; tile1 U0..U2 -> buf1
    stageU(0, Ac, Bc, 0);
    stageU(1, Ac, Bc, 0);
    stageU(2, Ac, Bc, 0);
    stageU(3, Ac, Bc, 0);
    stageU(0, An, Bn, 64);
    stageU(1, An, Bn, 64);
    stageU(2, An, Bn, 64);
    asm volatile("s_waitcnt vmcnt(6)" ::: "memory");
    __builtin_amdgcn_sched_barrier(0);
    __builtin_amdgcn_s_barrier();

    for (int w = 0; w < NT; ++w) {
        const int kc1 = (w + 1) << 6, kc2 = (w + 2) << 6;
        bf16x8 bfr[4][2], af[2][2];

        // ---------- phase 0: B frags + A mfrag 0,1 ----------
#pragma unroll
        for (int n = 0; n < 4; ++n) {
            int rB = (wn << 6) + n * 16 + l15;
#pragma unroll
            for (int kk = 0; kk < 2; ++kk) {
                int kb = kk * 4 + quad;
                bfr[n][kk] = *(const bf16x8*)&Bc[rB * 64 + ((kb ^ (rB & 7)) << 3)];
            }
        }
#pragma unroll
        for (int mm = 0; mm < 2; ++mm) {
            int rA = (wm << 7) + mm * 16 + l15;
#pragma unroll
            for (int kk = 0; kk < 2; ++kk) {
                int kb = kk * 4 + quad;
                af[mm][kk] = *(const bf16x8*)&Ac[rA * 64 + ((kb ^ (rA & 7)) << 3)];
            }
        }
        if (w + 1 < NT) stageU(3, An, Bn, kc1);
        __builtin_amdgcn_sched_barrier(0);
        __builtin_amdgcn_s_barrier();
        __builtin_amdgcn_sched_barrier(0);
        __builtin_amdgcn_s_setprio(1);
#pragma unroll
        for (int kk = 0; kk < 2; ++kk)
#pragma unroll
            for (int mm = 0; mm < 2; ++mm)
#pragma unroll
                for (int n = 0; n < 4; ++n)
                    acc[mm][n] = __builtin_amdgcn_mfma_f32_16x16x32_bf16(
                        af[mm][kk], bfr[n][kk], acc[mm][n], 0, 0, 0);
        __builtin_amdgcn_s_setprio(0);
        __builtin_amdgcn_sched_barrier(0);
        __builtin_amdgcn_s_barrier();

        // ---------- phases 1..3: A mfrag 2p,2p+1 ----------
#pragma unroll
        for (int ph = 1; ph < 4; ++ph) {
#pragma unroll
            for (int mm = 0; mm < 2; ++mm) {
                int rA = (wm << 7) + (ph * 2 + mm) * 16 + l15;
#pragma unroll
                for (int kk = 0; kk < 2; ++kk) {
                    int kb = kk * 4 + quad;
                    af[mm][kk] = *(const bf16x8*)&Ac[rA * 64 + ((kb ^ (rA & 7)) << 3)];
                }
            }
            if (w + 2 < NT) stageU(ph - 1, Ac, Bc, kc2);
            __builtin_amdgcn_sched_barrier(0);
            __builtin_amdgcn_s_barrier();
            __builtin_amdgcn_sched_barrier(0);
            __builtin_amdgcn_s_setprio(1);
#pragma unroll
            for (int kk = 0; kk < 2; ++kk)
#pragma unroll
                for (int mm = 0; mm < 2; ++mm)
#pragma unroll
                    for (int n = 0; n < 4; ++n)
                        acc[ph * 2 + mm][n] = __builtin_amdgcn_mfma_f32_16x16x32_bf16(
                            af[mm][kk], bfr[n][kk], acc[ph * 2 + mm][n], 0, 0, 0);
            __builtin_amdgcn_s_setprio(0);
            if (ph == 3) {
                if (w < NT - 2)
                    asm volatile("s_waitcnt vmcnt(6)" ::: "memory");
                else
                    asm volatile("s_waitcnt vmcnt(0)" ::: "memory");
            }
            __builtin_amdgcn_sched_barrier(0);
            __builtin_amdgcn_s_barrier();
        }

        short* t0 = Ac; Ac = An; An = t0;
        short* t1 = Bc; Bc = Bn; Bn = t1;
    }

    // ---------- epilogue: bias + relu + bf16 store ----------
    const int tmg = mt * 256 + (wm << 7);
    const int tng = nt * 256 + (wn << 6);
#pragma unroll
    for (int n = 0; n < 4; ++n) {
        int col = tng + n * 16 + l15;
        float bb = bias[col];
#pragma unroll
        for (int m = 0; m < 8; ++m) {
            int row0 = tmg + m * 16 + (quad << 2);
            f32x4 v = acc[m][n];
#pragma unroll
            for (int rr = 0; rr < 4; ++rr)
                Cout[(size_t)(row0 + rr) * N + col] = f2bf(fmaxf(v[rr] + bb, 0.f));
        }
    }
}

// GEMM3 + finalize. Block = 64 rows x 256 cols (full P row-slab), 4 waves.
__global__ __launch_bounds__(256) void gemm3_final(
    const short* __restrict__ H2, const short* __restrict__ W3T,
    const float* __restrict__ b3, const float* __restrict__ x,
    float* __restrict__ out, float* __restrict__ logdet) {
    constexpr int BK = 64, K = 1024;
    __shared__ __align__(16) char raw[40960];
    __shared__ float rowsum[64];
    short* As = (short*)raw;
    short* Bs = (short*)(raw + 8192);
    float* Tbuf = (float*)raw;
    const int tid = threadIdx.x;
    const int lane = tid & 63;
    const int wave = tid >> 6;
    const int tm = blockIdx.x * 64;
    const int srow = lane >> 3;
    const int skb = (lane & 7) ^ srow;
    const int l15 = lane & 15;
    const int quad = lane >> 4;

    if (tid < 64) rowsum[tid] = 0.f;

    f32x4 acc[4][4];
#pragma unroll
    for (int i = 0; i < 4; ++i)
#pragma unroll
        for (int j = 0; j < 4; ++j) acc[i][j] = f32x4{0.f, 0.f, 0.f, 0.f};

    for (int kc = 0; kc < K; kc += BK) {
        __syncthreads();
#pragma unroll
        for (int i = 0; i < 10; ++i) {       // 40 chunks: 8 A + 32 B
            int c = wave * 10 + i;
            if (c < 8) {
                int row = c * 8 + srow;
                gl2lds16(H2 + (size_t)(tm + row) * K + kc + skb * 8, &As[c * 512]);
            } else {
                int row = (c - 8) * 8 + srow;
                gl2lds16(W3T + (size_t)row * K + kc + skb * 8, &Bs[(c - 8) * 512]);
            }
        }
        __syncthreads();
#pragma unroll
        for (int kk = 0; kk < 2; ++kk) {
            int kb = kk * 4 + quad;
            bf16x8 af[4], bfr[4];
#pragma unroll
            for (int mt = 0; mt < 4; ++mt) {
                int r = mt * 16 + l15;
                af[mt] = *(const bf16x8*)&As[r * BK + ((kb ^ (r & 7)) << 3)];
            }
#pragma unroll
            for (int nt = 0; nt < 4; ++nt) {
                int n = wave * 64 + nt * 16 + l15;
                bfr[nt] = *(const bf16x8*)&Bs[n * BK + ((kb ^ (n & 7)) << 3)];
            }
#pragma unroll
            for (int mt = 0; mt < 4; ++mt)
#pragma unroll
                for (int nt = 0; nt < 4; ++nt)
                    acc[mt][nt] = __builtin_amdgcn_mfma_f32_16x16x32_bf16(
                        af[mt], bfr[nt], acc[mt][nt], 0, 0, 0);
        }
    }

    __syncthreads();
    if (wave >= 2) {
#pragma unroll
        for (int nt = 0; nt < 4; ++nt) {
            int col = wave * 64 + nt * 16 + l15;   // 128..255
            float bb = b3[col];
            int cl = col - 128;
#pragma unroll
            for (int mt = 0; mt < 4; ++mt) {
#pragma unroll
                for (int rr = 0; rr < 4; ++rr) {
                    int m = mt * 16 + quad * 4 + rr;
                    Tbuf[m * 132 + cl] = acc[mt][nt][rr] + bb;
                }
            }
        }
    }
    __syncthreads();
    if (wave < 2) {
#pragma unroll
        for (int mt = 0; mt < 4; ++mt) {
#pragma unroll
            for (int rr = 0; rr < 4; ++rr) {
                int m = mt * 16 + quad * 4 + rr;
                int grow = tm + m;
                float s = 0.f;
#pragma unroll
                for (int nt = 0; nt < 4; ++nt) {
                    int j = wave * 64 + nt * 16 + l15;   // 0..127
                    float p = acc[mt][nt][rr] + b3[j];
                    p = fminf(fmaxf(p, -15.f), 15.f);
                    float e2 = __expf(2.f * p);
                    float ls = (e2 - 1.f) / (e2 + 1.f);  // tanh(p)
                    s += ls;
                    float tt = Tbuf[m * 132 + j];
                    float2 xv = *(const float2*)&x[(size_t)grow * 256 + 2 * j];
                    float2 ov;
                    ov.x = xv.x;
                    ov.y = xv.y * __expf(ls) + tt;
                    *(float2*)&out[(size_t)grow * 256 + 2 * j] = ov;
                }
                s += __shfl_xor(s, 1);
                s += __shfl_xor(s, 2);
                s += __shfl_xor(s, 4);
                s += __shfl_xor(s, 8);
                if (l15 == 0) atomicAdd(&rowsum[m], s);
            }
        }
    }
    __syncthreads();
    if (tid < 64) logdet[tm + tid] = rowsum[tid];
}

extern "C" void kernel_launch(void* const* d_in, const int* in_sizes, int n_in,
                              void* d_out, int out_size, void* d_ws, size_t ws_size,
                              hipStream_t stream) {
    const float* x = (const float*)d_in[0];
    const float* cond = (const float*)d_in[1];
    const float* W1 = (const float*)d_in[2];
    const float* b1 = (const float*)d_in[3];
    const float* W2 = (const float*)d_in[4];
    const float* b2 = (const float*)d_in[5];
    const float* Wsp = (const float*)d_in[6];
    const float* bs = (const float*)d_in[7];
    const float* Wtp = (const float*)d_in[8];
    const float* bt = (const float*)d_in[9];

    char* ws = (char*)d_ws;
    short* W1T = (short*)(ws);                          // 1024x256 bf16 = 512 KB
    short* W2T = (short*)(ws + 524288ull);              // 1024x1024 bf16 = 2 MB
    short* W3T = (short*)(ws + 2621440ull);             // 256x1024 bf16 = 512 KB
    float* b3  = (float*)(ws + 3145728ull);             // 1 KB
    const size_t chunk_base = 3149824ull;

    // Per-chunk scratch: H1 = 2048*R, H2 = 2048*R.
    int n_chunks = 1;
    while (n_chunks < 512) {
        size_t rp = (size_t)B_ROWS / n_chunks;
        if (chunk_base + rp * 4096ull <= ws_size) break;
        n_chunks *= 2;
    }
    const size_t RP = (size_t)B_ROWS / n_chunks;

    float* out = (float*)d_out;
    float* logdet = out + (size_t)B_ROWS * D_DIM;

    transpose_bf16<<<(32768 + 255) / 256, 256, 0, stream>>>(W1, W1T, 256, 1024, 32768);
    transpose_bf16<<<(131072 + 255) / 256, 256, 0, stream>>>(W2, W2T, 1024, 1024, 131072);
    transpose_bf16<<<(16384 + 255) / 256, 256, 0, stream>>>(Wsp, W3T, 1024, 128, 16384);
    transpose_bf16<<<(16384 + 255) / 256, 256, 0, stream>>>(Wtp, W3T + 131072, 1024, 128, 16384);
    prep_b3<<<1, 256, 0, stream>>>(bs, bt, b3);

    for (int c = 0; c < n_chunks; ++c) {
        const size_t r0 = (size_t)c * RP;
        short* H1 = (short*)(ws + chunk_base);
        short* H2 = (short*)(ws + chunk_base + 2048ull * RP);
        const int mtiles = (int)(RP / 128);

        gemm1_fused<<<mtiles * 8, 256, 0, stream>>>(
            x + r0 * D_DIM, cond + r0 * C_DIM, W1T, b1, (unsigned short*)H1, mtiles);
        if ((RP & 255) == 0) {
            gemm2_8ph<<<(int)(RP / 256) * 4, 512, 0, stream>>>(
                H1, W2T, b2, (unsigned short*)H2);
        } else {
            gemm_tn<<<mtiles * 8, 256, 0, stream>>>(
                H1, W2T, b2, (unsigned short*)H2, mtiles, H_DIM, H_DIM);
        }
        gemm3_final<<<(int)(RP / 64), 256, 0, stream>>>(
            H2, W3T, b3, x + r0 * D_DIM, out + r0 * D_DIM, logdet + r0);
    }
}

// Round 3
// 477.306 us; speedup vs baseline: 1.0648x; 1.0282x over previous
//
#include <hip/hip_runtime.h>
#include <hip/hip_bf16.h>
#include <math.h>

#define B_ROWS 65536
#define D_DIM 256
#define C_DIM 128
#define H_DIM 1024

typedef __bf16 bf16x8 __attribute__((ext_vector_type(8)));
typedef float f32x4 __attribute__((ext_vector_type(4)));
typedef short short8 __attribute__((ext_vector_type(8)));

__device__ __forceinline__ unsigned short f2bf(float f) {
    unsigned int u = __float_as_uint(f);
    u += 0x7fffu + ((u >> 16) & 1u);
    return (unsigned short)(u >> 16);
}

__device__ __forceinline__ void gl2lds16(const void* g, void* l) {
    __builtin_amdgcn_global_load_lds(
        (const __attribute__((address_space(1))) unsigned int*)g,
        (__attribute__((address_space(3))) unsigned int*)l, 16, 0, 0);
}

// Opaque LDS read via a proper address_space(3) pointer (32-bit LDS address,
// no flat-aperture truncation). Compiler does not model the dependency on
// outstanding global_load_lds, so it cannot insert a conservative vmcnt(0)
// drain; correctness comes from our explicit barriers + counted vmcnt.
__device__ __forceinline__ bf16x8 ds_read_b128_asm(const short* p) {
    bf16x8 r;
    asm volatile("ds_read_b128 %0, %1"
                 : "=v"(r)
                 : "v"((const __attribute__((address_space(3))) short*)p));
    return r;
}

// XCD-aware swizzle: all 8 N-tiles of one M-tile land on the same XCD.
__device__ __forceinline__ void swizzle_mn(int id, int mtiles, int& m, int& n) {
    if ((mtiles & 7) == 0) {
        int g = id >> 6, r = id & 63;
        m = g * 8 + (r & 7);
        n = r >> 3;
    } else {
        m = id >> 3;
        n = id & 7;
    }
}

// dst[n*R + k] = bf16(src[k*C + n]); src is R x C row-major, dst N x K
__global__ void transpose_bf16(const float* __restrict__ src, short* __restrict__ dst,
                               int R, int C, int total) {
    int tid = blockIdx.x * 256 + threadIdx.x;
    if (tid >= total) return;
    int per = R >> 3;
    int n = tid / per;
    int k0 = (tid - n * per) << 3;
    short8 o;
#pragma unroll
    for (int j = 0; j < 8; ++j) o[j] = (short)f2bf(src[(size_t)(k0 + j) * C + n]);
    *(short8*)&dst[(size_t)n * R + k0] = o;
}

__global__ void prep_b3(const float* __restrict__ bs, const float* __restrict__ bt,
                        float* __restrict__ b3) {
    int i = threadIdx.x;
    b3[i] = (i < 128) ? bs[i] : bt[i - 128];
}

// GEMM1 fused: A[m][k] = k<128 ? x[m][2k] : cond[m][k-128], B = W1T (1024 x 256).
// H1 = relu(A@W1 + b1) bf16.
__global__ __launch_bounds__(256) void gemm1_fused(
    const float* __restrict__ x, const float* __restrict__ cond,
    const short* __restrict__ Bw, const float* __restrict__ bias,
    unsigned short* __restrict__ H1, int mtiles) {
    constexpr int BK = 64, K = 256, N = 1024;
    __shared__ __align__(16) short As[128 * BK];
    __shared__ __align__(16) short Bs[128 * BK];
    const int tid = threadIdx.x;
    const int lane = tid & 63;
    const int wave = tid >> 6;
    int mt, nt;
    swizzle_mn(blockIdx.x, mtiles, mt, nt);
    const int tm = mt * 128, tn = nt * 128;
    const int mo = (wave >> 1) * 64;
    const int no = (wave & 1) * 64;

    f32x4 acc[4][4];
#pragma unroll
    for (int i = 0; i < 4; ++i)
#pragma unroll
        for (int j = 0; j < 4; ++j) acc[i][j] = f32x4{0.f, 0.f, 0.f, 0.f};

    const int srow = lane >> 3;
    const int skb = (lane & 7) ^ srow;

#pragma unroll
    for (int kc = 0; kc < K; kc += BK) {
        __syncthreads();
#pragma unroll
        for (int i = 0; i < 4; ++i) {
            int c = wave * 4 + i;
            int row = c * 8 + srow;
            int kcol = kc + skb * 8;
            float v[8];
            if (kc < 128) {
                const float4* p = (const float4*)(x + (size_t)(tm + row) * 256 + 2 * kcol);
                float4 a = p[0], b = p[1], cc = p[2], d = p[3];
                v[0]=a.x; v[1]=a.z; v[2]=b.x; v[3]=b.z; v[4]=cc.x; v[5]=cc.z; v[6]=d.x; v[7]=d.z;
            } else {
                const float4* p = (const float4*)(cond + (size_t)(tm + row) * 128 + (kcol - 128));
                float4 a = p[0], b = p[1];
                v[0]=a.x; v[1]=a.y; v[2]=a.z; v[3]=a.w; v[4]=b.x; v[5]=b.y; v[6]=b.z; v[7]=b.w;
            }
            short8 o;
#pragma unroll
            for (int j = 0; j < 8; ++j) o[j] = (short)f2bf(v[j]);
            *(short8*)&As[c * 512 + lane * 8] = o;
            gl2lds16(Bw + (size_t)(tn + row) * K + kc + skb * 8, &Bs[c * 512]);
        }
        __syncthreads();
#pragma unroll
        for (int kk = 0; kk < 2; ++kk) {
            bf16x8 af[4], bfr[4];
            int kb = kk * 4 + (lane >> 4);
#pragma unroll
            for (int t = 0; t < 4; ++t) {
                int r = mo + t * 16 + (lane & 15);
                af[t] = *(const bf16x8*)&As[r * BK + ((kb ^ (r & 7)) << 3)];
                int n = no + t * 16 + (lane & 15);
                bfr[t] = *(const bf16x8*)&Bs[n * BK + ((kb ^ (n & 7)) << 3)];
            }
#pragma unroll
            for (int i = 0; i < 4; ++i)
#pragma unroll
                for (int j = 0; j < 4; ++j)
                    acc[i][j] = __builtin_amdgcn_mfma_f32_16x16x32_bf16(
                        af[i], bfr[j], acc[i][j], 0, 0, 0);
        }
    }

#pragma unroll
    for (int j = 0; j < 4; ++j) {
        int col = tn + no + j * 16 + (lane & 15);
        float bb = bias[col];
#pragma unroll
        for (int i = 0; i < 4; ++i) {
            int row0 = tm + mo + i * 16 + ((lane >> 4) << 2);
            f32x4 v = acc[i][j];
#pragma unroll
            for (int rr = 0; rr < 4; ++rr)
                H1[(size_t)(row0 + rr) * N + col] = f2bf(fmaxf(v[rr] + bb, 0.f));
        }
    }
}

// Fallback GEMM2 (old 128x128 structure), only used if RP % 256 != 0.
__global__ __launch_bounds__(256) void gemm_tn(
    const short* __restrict__ A, const short* __restrict__ Bw,
    const float* __restrict__ bias, unsigned short* __restrict__ Cout,
    int mtiles, int N, int K) {
    constexpr int BK = 64;
    __shared__ __align__(16) short As[128 * BK];
    __shared__ __align__(16) short Bs[128 * BK];
    const int tid = threadIdx.x;
    const int lane = tid & 63;
    const int wave = tid >> 6;
    int mt, nt;
    swizzle_mn(blockIdx.x, mtiles, mt, nt);
    const int tm = mt * 128, tn = nt * 128;
    const int mo = (wave >> 1) * 64;
    const int no = (wave & 1) * 64;

    f32x4 acc[4][4];
#pragma unroll
    for (int i = 0; i < 4; ++i)
#pragma unroll
        for (int j = 0; j < 4; ++j) acc[i][j] = f32x4{0.f, 0.f, 0.f, 0.f};

    const int srow = lane >> 3;
    const int skb = (lane & 7) ^ srow;

    for (int kc = 0; kc < K; kc += BK) {
        __syncthreads();
#pragma unroll
        for (int i = 0; i < 4; ++i) {
            int c = wave * 4 + i;
            int row = c * 8 + srow;
            gl2lds16(A + (size_t)(tm + row) * K + kc + skb * 8, &As[c * 512]);
            gl2lds16(Bw + (size_t)(tn + row) * K + kc + skb * 8, &Bs[c * 512]);
        }
        __syncthreads();
#pragma unroll
        for (int kk = 0; kk < 2; ++kk) {
            bf16x8 af[4], bfr[4];
            int kb = kk * 4 + (lane >> 4);
#pragma unroll
            for (int t = 0; t < 4; ++t) {
                int r = mo + t * 16 + (lane & 15);
                af[t] = *(const bf16x8*)&As[r * BK + ((kb ^ (r & 7)) << 3)];
                int n = no + t * 16 + (lane & 15);
                bfr[t] = *(const bf16x8*)&Bs[n * BK + ((kb ^ (n & 7)) << 3)];
            }
#pragma unroll
            for (int i = 0; i < 4; ++i)
#pragma unroll
                for (int j = 0; j < 4; ++j)
                    acc[i][j] = __builtin_amdgcn_mfma_f32_16x16x32_bf16(
                        af[i], bfr[j], acc[i][j], 0, 0, 0);
        }
    }

#pragma unroll
    for (int j = 0; j < 4; ++j) {
        int col = tn + no + j * 16 + (lane & 15);
        float bb = bias[col];
#pragma unroll
        for (int i = 0; i < 4; ++i) {
            int row0 = tm + mo + i * 16 + ((lane >> 4) << 2);
            f32x4 v = acc[i][j];
#pragma unroll
            for (int rr = 0; rr < 4; ++rr)
                Cout[(size_t)(row0 + rr) * N + col] = f2bf(fmaxf(v[rr] + bb, 0.f));
        }
    }
}

// ===========================================================================
// GEMM2, 256x256 tile, BK=64, 8 waves (2M x 4N), 4 phases/K-tile, counted
// vmcnt (T2+T3+T4+T5).
//  - inline-asm ds_read_b128 (AS3 pointer) for all fragment reads: compiler
//    cannot see the LDS dependency -> no conservative vmcnt(0) drains
//  - static buffer alternation: single smem[] with constant offsets, window
//    loop unrolled x2, no pointer swap
//  - explicit s_waitcnt lgkmcnt(0) + sched_barrier(0) after each barrier
//    (rule #18) before the MFMA cluster
//  - epilogue staged through LDS -> full-line dwordx4 stores (scalar 2B
//    stores caused 2x HBM write amplification: 124 MB vs 64 MB ideal)
// vmcnt ledger (steady state): enter window with 6 outstanding (U0-U2 of
// tile w+1); p0 +U3(w+1)=8; p1-p3 +U0-U2(w+2)=14; vmcnt(6) at p3 drains the
// 8 oldest = exactly tile w+1; barrier publishes across waves.
// ===========================================================================
__global__ __launch_bounds__(512, 2) void gemm2_8ph(
    const short* __restrict__ A, const short* __restrict__ Bw,
    const float* __restrict__ bias, unsigned short* __restrict__ Cout) {
    constexpr int K = 1024, NT = 16;           // 16 K-tiles of 64
    constexpr unsigned OFF_A0 = 0, OFF_B0 = 16384, OFF_A1 = 32768, OFF_B1 = 49152;
    __shared__ __align__(16) short smem[65536];   // 128 KB

    const int tid = threadIdx.x;
    const int lane = tid & 63;
    const int wave = tid >> 6;      // 0..7
    const int wm = wave >> 2;       // 0..1  -> 128-row half
    const int wn = wave & 3;        // 0..3  -> 64-col quarter
    const int l15 = lane & 15;
    const int quad = lane >> 4;
    const int srow = lane >> 3;
    const int skb8 = ((lane & 7) ^ srow) << 3;

    // bijective XCD swizzle
    const int id = blockIdx.x, nwg = gridDim.x;
    const int xcd = id & 7, lid = id >> 3;
    const int q = nwg >> 3, r = nwg & 7;
    const int wgid = (xcd < r ? xcd * (q + 1) : r * (q + 1) + (xcd - r) * q) + lid;
    const int mt = wgid >> 2, nt = wgid & 3;    // 4 n-tiles (N=1024)
    const size_t Abase = (size_t)(mt * 256) * K;
    const size_t Bbase = (size_t)(nt * 256) * K;

    f32x4 acc[8][4];
#pragma unroll
    for (int m = 0; m < 8; ++m)
#pragma unroll
        for (int n = 0; n < 4; ++n) acc[m][n] = f32x4{0.f, 0.f, 0.f, 0.f};

    auto stage2 = [&](unsigned off, const short* g, size_t rowbase, int kc, int c0, int c1) {
        gl2lds16(g + rowbase + (size_t)(c0 * 8 + srow) * K + kc + skb8, smem + off + c0 * 512);
        gl2lds16(g + rowbase + (size_t)(c1 * 8 + srow) * K + kc + skb8, smem + off + c1 * 512);
    };
    auto stageU = [&](int u, unsigned aOff, unsigned bOff, int kc) {
        if (u == 0)      stage2(bOff, Bw, Bbase, kc, wave * 2, wave * 2 + 1);
        else if (u == 1) stage2(bOff, Bw, Bbase, kc, 16 + wave * 2, 17 + wave * 2);
        else if (u == 2) stage2(aOff, A, Abase, kc, wave, 16 + wave);
        else             stage2(aOff, A, Abase, kc, 8 + wave, 24 + wave);
    };

    // per-lane constant pieces of the swizzled fragment offsets (in shorts)
    // frag offset = row*64 + ((kb ^ (row&7))<<3); row&7 == l15&7
    const unsigned x0 = (unsigned)((quad ^ (l15 & 7)) << 3);          // kk=0
    const unsigned x1 = (unsigned)(((4 + quad) ^ (l15 & 7)) << 3);    // kk=1

    auto window = [&](int w, unsigned caOff, unsigned cbOff, unsigned naOff, unsigned nbOff) {
        const int kc1 = (w + 1) << 6, kc2 = (w + 2) << 6;
        const short* aA = smem + caOff + ((wm << 7) + l15) * 64;
        const short* aB = smem + cbOff + ((wn << 6) + l15) * 64;
        bf16x8 bfr[4][2], af[2][2];

        // ---------- phase 0: stage U3(w+1)->next; read B frags + A mfrag 0,1
        if (w + 1 < NT) stageU(3, naOff, nbOff, kc1);
#pragma unroll
        for (int n = 0; n < 4; ++n) {
            bfr[n][0] = ds_read_b128_asm(aB + n * 1024 + x0);
            bfr[n][1] = ds_read_b128_asm(aB + n * 1024 + x1);
        }
#pragma unroll
        for (int mm = 0; mm < 2; ++mm) {
            af[mm][0] = ds_read_b128_asm(aA + mm * 1024 + x0);
            af[mm][1] = ds_read_b128_asm(aA + mm * 1024 + x1);
        }
        __builtin_amdgcn_sched_barrier(0);
        __builtin_amdgcn_s_barrier();
        asm volatile("s_waitcnt lgkmcnt(0)" ::: "memory");
        __builtin_amdgcn_sched_barrier(0);
        __builtin_amdgcn_s_setprio(1);
#pragma unroll
        for (int kk = 0; kk < 2; ++kk)
#pragma unroll
            for (int mm = 0; mm < 2; ++mm)
#pragma unroll
                for (int n = 0; n < 4; ++n)
                    acc[mm][n] = __builtin_amdgcn_mfma_f32_16x16x32_bf16(
                        af[mm][kk], bfr[n][kk], acc[mm][n], 0, 0, 0);
        __builtin_amdgcn_s_setprio(0);
        __builtin_amdgcn_sched_barrier(0);
        __builtin_amdgcn_s_barrier();

        // ---------- phases 1..3: stage U(ph-1)(w+2)->cur; read A mfrag 2p,2p+1
#pragma unroll
        for (int ph = 1; ph < 4; ++ph) {
            if (w + 2 < NT) stageU(ph - 1, caOff, cbOff, kc2);
#pragma unroll
            for (int mm = 0; mm < 2; ++mm) {
                af[mm][0] = ds_read_b128_asm(aA + (ph * 2 + mm) * 1024 + x0);
                af[mm][1] = ds_read_b128_asm(aA + (ph * 2 + mm) * 1024 + x1);
            }
            __builtin_amdgcn_sched_barrier(0);
            __builtin_amdgcn_s_barrier();
            asm volatile("s_waitcnt lgkmcnt(0)" ::: "memory");
            __builtin_amdgcn_sched_barrier(0);
            __builtin_amdgcn_s_setprio(1);
#pragma unroll
            for (int kk = 0; kk < 2; ++kk)
#pragma unroll
                for (int mm = 0; mm < 2; ++mm)
#pragma unroll
                    for (int n = 0; n < 4; ++n)
                        acc[ph * 2 + mm][n] = __builtin_amdgcn_mfma_f32_16x16x32_bf16(
                            af[mm][kk], bfr[n][kk], acc[ph * 2 + mm][n], 0, 0, 0);
            __builtin_amdgcn_s_setprio(0);
            if (ph == 3) {
                if (w < NT - 2)
                    asm volatile("s_waitcnt vmcnt(6)" ::: "memory");
                else
                    asm volatile("s_waitcnt vmcnt(0)" ::: "memory");
            }
            __builtin_amdgcn_sched_barrier(0);
            __builtin_amdgcn_s_barrier();
        }
    };

    // ---- prologue: tile0 complete -> buf0; tile1 U0..U2 -> buf1
    stageU(0, OFF_A0, OFF_B0, 0);
    stageU(1, OFF_A0, OFF_B0, 0);
    stageU(2, OFF_A0, OFF_B0, 0);
    stageU(3, OFF_A0, OFF_B0, 0);
    stageU(0, OFF_A1, OFF_B1, 64);
    stageU(1, OFF_A1, OFF_B1, 64);
    stageU(2, OFF_A1, OFF_B1, 64);
    asm volatile("s_waitcnt vmcnt(6)" ::: "memory");
    __builtin_amdgcn_sched_barrier(0);
    __builtin_amdgcn_s_barrier();

#pragma unroll 1
    for (int w = 0; w < NT; w += 2) {
        window(w, OFF_A0, OFF_B0, OFF_A1, OFF_B1);
        window(w + 1, OFF_A1, OFF_B1, OFF_A0, OFF_B0);
    }

    // ---------- epilogue: bias+relu -> LDS bf16 [256][256] -> coalesced store
    __syncthreads();
    unsigned short* cs = (unsigned short*)smem;
#pragma unroll
    for (int n = 0; n < 4; ++n) {
        int col = (wn << 6) + n * 16 + l15;
        float bb = bias[nt * 256 + col];
#pragma unroll
        for (int m = 0; m < 8; ++m) {
            int row = (wm << 7) + m * 16 + (quad << 2);
#pragma unroll
            for (int rr = 0; rr < 4; ++rr)
                cs[(row + rr) * 256 + col] = f2bf(fmaxf(acc[m][n][rr] + bb, 0.f));
        }
    }
    __syncthreads();
    const size_t cbase = (size_t)(mt * 256) * 1024 + nt * 256;
    const int rloc = tid >> 5, cchunk = tid & 31;
#pragma unroll
    for (int rnd = 0; rnd < 16; ++rnd) {
        int rw = rnd * 16 + rloc;
        short8 v = *(const short8*)&cs[rw * 256 + cchunk * 8];
        *(short8*)((unsigned short*)Cout + cbase + (size_t)rw * 1024 + cchunk * 8) = v;
    }
}

// GEMM3 + finalize. Block = 64 rows x 256 cols (full P row-slab), 4 waves.
__global__ __launch_bounds__(256) void gemm3_final(
    const short* __restrict__ H2, const short* __restrict__ W3T,
    const float* __restrict__ b3, const float* __restrict__ x,
    float* __restrict__ out, float* __restrict__ logdet) {
    constexpr int BK = 64, K = 1024;
    __shared__ __align__(16) char raw[40960];
    __shared__ float rowsum[64];
    short* As = (short*)raw;
    short* Bs = (short*)(raw + 8192);
    float* Tbuf = (float*)raw;
    const int tid = threadIdx.x;
    const int lane = tid & 63;
    const int wave = tid >> 6;
    const int tm = blockIdx.x * 64;
    const int srow = lane >> 3;
    const int skb = (lane & 7) ^ srow;
    const int l15 = lane & 15;
    const int quad = lane >> 4;

    if (tid < 64) rowsum[tid] = 0.f;

    f32x4 acc[4][4];
#pragma unroll
    for (int i = 0; i < 4; ++i)
#pragma unroll
        for (int j = 0; j < 4; ++j) acc[i][j] = f32x4{0.f, 0.f, 0.f, 0.f};

    for (int kc = 0; kc < K; kc += BK) {
        __syncthreads();
#pragma unroll
        for (int i = 0; i < 10; ++i) {       // 40 chunks: 8 A + 32 B
            int c = wave * 10 + i;
            if (c < 8) {
                int row = c * 8 + srow;
                gl2lds16(H2 + (size_t)(tm + row) * K + kc + skb * 8, &As[c * 512]);
            } else {
                int row = (c - 8) * 8 + srow;
                gl2lds16(W3T + (size_t)row * K + kc + skb * 8, &Bs[(c - 8) * 512]);
            }
        }
        __syncthreads();
#pragma unroll
        for (int kk = 0; kk < 2; ++kk) {
            int kb = kk * 4 + quad;
            bf16x8 af[4], bfr[4];
#pragma unroll
            for (int mt = 0; mt < 4; ++mt) {
                int r = mt * 16 + l15;
                af[mt] = *(const bf16x8*)&As[r * BK + ((kb ^ (r & 7)) << 3)];
            }
#pragma unroll
            for (int nt = 0; nt < 4; ++nt) {
                int n = wave * 64 + nt * 16 + l15;
                bfr[nt] = *(const bf16x8*)&Bs[n * BK + ((kb ^ (n & 7)) << 3)];
            }
#pragma unroll
            for (int mt = 0; mt < 4; ++mt)
#pragma unroll
                for (int nt = 0; nt < 4; ++nt)
                    acc[mt][nt] = __builtin_amdgcn_mfma_f32_16x16x32_bf16(
                        af[mt], bfr[nt], acc[mt][nt], 0, 0, 0);
        }
    }

    __syncthreads();
    if (wave >= 2) {
#pragma unroll
        for (int nt = 0; nt < 4; ++nt) {
            int col = wave * 64 + nt * 16 + l15;   // 128..255
            float bb = b3[col];
            int cl = col - 128;
#pragma unroll
            for (int mt = 0; mt < 4; ++mt) {
#pragma unroll
                for (int rr = 0; rr < 4; ++rr) {
                    int m = mt * 16 + quad * 4 + rr;
                    Tbuf[m * 132 + cl] = acc[mt][nt][rr] + bb;
                }
            }
        }
    }
    __syncthreads();
    if (wave < 2) {
#pragma unroll
        for (int mt = 0; mt < 4; ++mt) {
#pragma unroll
            for (int rr = 0; rr < 4; ++rr) {
                int m = mt * 16 + quad * 4 + rr;
                int grow = tm + m;
                float s = 0.f;
#pragma unroll
                for (int nt = 0; nt < 4; ++nt) {
                    int j = wave * 64 + nt * 16 + l15;   // 0..127
                    float p = acc[mt][nt][rr] + b3[j];
                    p = fminf(fmaxf(p, -15.f), 15.f);
                    float e2 = __expf(2.f * p);
                    float ls = (e2 - 1.f) / (e2 + 1.f);  // tanh(p)
                    s += ls;
                    float tt = Tbuf[m * 132 + j];
                    float2 xv = *(const float2*)&x[(size_t)grow * 256 + 2 * j];
                    float2 ov;
                    ov.x = xv.x;
                    ov.y = xv.y * __expf(ls) + tt;
                    *(float2*)&out[(size_t)grow * 256 + 2 * j] = ov;
                }
                s += __shfl_xor(s, 1);
                s += __shfl_xor(s, 2);
                s += __shfl_xor(s, 4);
                s += __shfl_xor(s, 8);
                if (l15 == 0) atomicAdd(&rowsum[m], s);
            }
        }
    }
    __syncthreads();
    if (tid < 64) logdet[tm + tid] = rowsum[tid];
}

extern "C" void kernel_launch(void* const* d_in, const int* in_sizes, int n_in,
                              void* d_out, int out_size, void* d_ws, size_t ws_size,
                              hipStream_t stream) {
    const float* x = (const float*)d_in[0];
    const float* cond = (const float*)d_in[1];
    const float* W1 = (const float*)d_in[2];
    const float* b1 = (const float*)d_in[3];
    const float* W2 = (const float*)d_in[4];
    const float* b2 = (const float*)d_in[5];
    const float* Wsp = (const float*)d_in[6];
    const float* bs = (const float*)d_in[7];
    const float* Wtp = (const float*)d_in[8];
    const float* bt = (const float*)d_in[9];

    char* ws = (char*)d_ws;
    short* W1T = (short*)(ws);                          // 1024x256 bf16 = 512 KB
    short* W2T = (short*)(ws + 524288ull);              // 1024x1024 bf16 = 2 MB
    short* W3T = (short*)(ws + 2621440ull);             // 256x1024 bf16 = 512 KB
    float* b3  = (float*)(ws + 3145728ull);             // 1 KB
    const size_t chunk_base = 3149824ull;

    // Per-chunk scratch: H1 = 2048*R, H2 = 2048*R.
    int n_chunks = 1;
    while (n_chunks < 512) {
        size_t rp = (size_t)B_ROWS / n_chunks;
        if (chunk_base + rp * 4096ull <= ws_size) break;
        n_chunks *= 2;
    }
    const size_t RP = (size_t)B_ROWS / n_chunks;

    float* out = (float*)d_out;
    float* logdet = out + (size_t)B_ROWS * D_DIM;

    transpose_bf16<<<(32768 + 255) / 256, 256, 0, stream>>>(W1, W1T, 256, 1024, 32768);
    transpose_bf16<<<(131072 + 255) / 256, 256, 0, stream>>>(W2, W2T, 1024, 1024, 131072);
    transpose_bf16<<<(16384 + 255) / 256, 256, 0, stream>>>(Wsp, W3T, 1024, 128, 16384);
    transpose_bf16<<<(16384 + 255) / 256, 256, 0, stream>>>(Wtp, W3T + 131072, 1024, 128, 16384);
    prep_b3<<<1, 256, 0, stream>>>(bs, bt, b3);

    for (int c = 0; c < n_chunks; ++c) {
        const size_t r0 = (size_t)c * RP;
        short* H1 = (short*)(ws + chunk_base);
        short* H2 = (short*)(ws + chunk_base + 2048ull * RP);
        const int mtiles = (int)(RP / 128);

        gemm1_fused<<<mtiles * 8, 256, 0, stream>>>(
            x + r0 * D_DIM, cond + r0 * C_DIM, W1T, b1, (unsigned short*)H1, mtiles);
        if ((RP & 255) == 0) {
            gemm2_8ph<<<(int)(RP / 256) * 4, 512, 0, stream>>>(
                H1, W2T, b2, (unsigned short*)H2);
        } else {
            gemm_tn<<<mtiles * 8, 256, 0, stream>>>(
                H1, W2T, b2, (unsigned short*)H2, mtiles, H_DIM, H_DIM);
        }
        gemm3_final<<<(int)(RP / 64), 256, 0, stream>>>(
            H2, W3T, b3, x + r0 * D_DIM, out + r0 * D_DIM, logdet + r0);
    }
}

// Round 4
// 471.373 us; speedup vs baseline: 1.0782x; 1.0126x over previous
//
#include <hip/hip_runtime.h>
#include <hip/hip_bf16.h>
#include <math.h>

#define B_ROWS 65536
#define D_DIM 256
#define C_DIM 128
#define H_DIM 1024

typedef __bf16 bf16x8 __attribute__((ext_vector_type(8)));
typedef float f32x4 __attribute__((ext_vector_type(4)));
typedef short short8 __attribute__((ext_vector_type(8)));

__device__ __forceinline__ unsigned short f2bf(float f) {
    unsigned int u = __float_as_uint(f);
    u += 0x7fffu + ((u >> 16) & 1u);
    return (unsigned short)(u >> 16);
}

__device__ __forceinline__ void gl2lds16(const void* g, void* l) {
    __builtin_amdgcn_global_load_lds(
        (const __attribute__((address_space(1))) unsigned int*)g,
        (__attribute__((address_space(3))) unsigned int*)l, 16, 0, 0);
}

// Opaque LDS read via a proper address_space(3) pointer (32-bit LDS address,
// no flat-aperture truncation). Compiler does not model the dependency on
// outstanding global_load_lds, so it cannot insert a conservative vmcnt(0)
// drain; correctness comes from our explicit barriers + counted vmcnt.
__device__ __forceinline__ bf16x8 ds_read_b128_asm(const short* p) {
    bf16x8 r;
    asm volatile("ds_read_b128 %0, %1"
                 : "=v"(r)
                 : "v"((const __attribute__((address_space(3))) short*)p));
    return r;
}

// XCD-aware swizzle: all 8 N-tiles of one M-tile land on the same XCD.
__device__ __forceinline__ void swizzle_mn(int id, int mtiles, int& m, int& n) {
    if ((mtiles & 7) == 0) {
        int g = id >> 6, r = id & 63;
        m = g * 8 + (r & 7);
        n = r >> 3;
    } else {
        m = id >> 3;
        n = id & 7;
    }
}

// dst[n*R + k] = bf16(src[k*C + n]); src is R x C row-major, dst N x K
__global__ void transpose_bf16(const float* __restrict__ src, short* __restrict__ dst,
                               int R, int C, int total) {
    int tid = blockIdx.x * 256 + threadIdx.x;
    if (tid >= total) return;
    int per = R >> 3;
    int n = tid / per;
    int k0 = (tid - n * per) << 3;
    short8 o;
#pragma unroll
    for (int j = 0; j < 8; ++j) o[j] = (short)f2bf(src[(size_t)(k0 + j) * C + n]);
    *(short8*)&dst[(size_t)n * R + k0] = o;
}

__global__ void prep_b3(const float* __restrict__ bs, const float* __restrict__ bt,
                        float* __restrict__ b3) {
    int i = threadIdx.x;
    b3[i] = (i < 128) ? bs[i] : bt[i - 128];
}

// GEMM1 fused: A[m][k] = k<128 ? x[m][2k] : cond[m][k-128], B = W1T (1024 x 256).
// H1 = relu(A@W1 + b1) bf16.
__global__ __launch_bounds__(256) void gemm1_fused(
    const float* __restrict__ x, const float* __restrict__ cond,
    const short* __restrict__ Bw, const float* __restrict__ bias,
    unsigned short* __restrict__ H1, int mtiles) {
    constexpr int BK = 64, K = 256, N = 1024;
    __shared__ __align__(16) short As[128 * BK];
    __shared__ __align__(16) short Bs[128 * BK];
    const int tid = threadIdx.x;
    const int lane = tid & 63;
    const int wave = tid >> 6;
    int mt, nt;
    swizzle_mn(blockIdx.x, mtiles, mt, nt);
    const int tm = mt * 128, tn = nt * 128;
    const int mo = (wave >> 1) * 64;
    const int no = (wave & 1) * 64;

    f32x4 acc[4][4];
#pragma unroll
    for (int i = 0; i < 4; ++i)
#pragma unroll
        for (int j = 0; j < 4; ++j) acc[i][j] = f32x4{0.f, 0.f, 0.f, 0.f};

    const int srow = lane >> 3;
    const int skb = (lane & 7) ^ srow;

#pragma unroll
    for (int kc = 0; kc < K; kc += BK) {
        __syncthreads();
#pragma unroll
        for (int i = 0; i < 4; ++i) {
            int c = wave * 4 + i;
            int row = c * 8 + srow;
            int kcol = kc + skb * 8;
            float v[8];
            if (kc < 128) {
                const float4* p = (const float4*)(x + (size_t)(tm + row) * 256 + 2 * kcol);
                float4 a = p[0], b = p[1], cc = p[2], d = p[3];
                v[0]=a.x; v[1]=a.z; v[2]=b.x; v[3]=b.z; v[4]=cc.x; v[5]=cc.z; v[6]=d.x; v[7]=d.z;
            } else {
                const float4* p = (const float4*)(cond + (size_t)(tm + row) * 128 + (kcol - 128));
                float4 a = p[0], b = p[1];
                v[0]=a.x; v[1]=a.y; v[2]=a.z; v[3]=a.w; v[4]=b.x; v[5]=b.y; v[6]=b.z; v[7]=b.w;
            }
            short8 o;
#pragma unroll
            for (int j = 0; j < 8; ++j) o[j] = (short)f2bf(v[j]);
            *(short8*)&As[c * 512 + lane * 8] = o;
            gl2lds16(Bw + (size_t)(tn + row) * K + kc + skb * 8, &Bs[c * 512]);
        }
        __syncthreads();
#pragma unroll
        for (int kk = 0; kk < 2; ++kk) {
            bf16x8 af[4], bfr[4];
            int kb = kk * 4 + (lane >> 4);
#pragma unroll
            for (int t = 0; t < 4; ++t) {
                int r = mo + t * 16 + (lane & 15);
                af[t] = *(const bf16x8*)&As[r * BK + ((kb ^ (r & 7)) << 3)];
                int n = no + t * 16 + (lane & 15);
                bfr[t] = *(const bf16x8*)&Bs[n * BK + ((kb ^ (n & 7)) << 3)];
            }
#pragma unroll
            for (int i = 0; i < 4; ++i)
#pragma unroll
                for (int j = 0; j < 4; ++j)
                    acc[i][j] = __builtin_amdgcn_mfma_f32_16x16x32_bf16(
                        af[i], bfr[j], acc[i][j], 0, 0, 0);
        }
    }

#pragma unroll
    for (int j = 0; j < 4; ++j) {
        int col = tn + no + j * 16 + (lane & 15);
        float bb = bias[col];
#pragma unroll
        for (int i = 0; i < 4; ++i) {
            int row0 = tm + mo + i * 16 + ((lane >> 4) << 2);
            f32x4 v = acc[i][j];
#pragma unroll
            for (int rr = 0; rr < 4; ++rr)
                H1[(size_t)(row0 + rr) * N + col] = f2bf(fmaxf(v[rr] + bb, 0.f));
        }
    }
}

// Fallback GEMM2 (old 128x128 structure), only used if RP % 256 != 0.
__global__ __launch_bounds__(256) void gemm_tn(
    const short* __restrict__ A, const short* __restrict__ Bw,
    const float* __restrict__ bias, unsigned short* __restrict__ Cout,
    int mtiles, int N, int K) {
    constexpr int BK = 64;
    __shared__ __align__(16) short As[128 * BK];
    __shared__ __align__(16) short Bs[128 * BK];
    const int tid = threadIdx.x;
    const int lane = tid & 63;
    const int wave = tid >> 6;
    int mt, nt;
    swizzle_mn(blockIdx.x, mtiles, mt, nt);
    const int tm = mt * 128, tn = nt * 128;
    const int mo = (wave >> 1) * 64;
    const int no = (wave & 1) * 64;

    f32x4 acc[4][4];
#pragma unroll
    for (int i = 0; i < 4; ++i)
#pragma unroll
        for (int j = 0; j < 4; ++j) acc[i][j] = f32x4{0.f, 0.f, 0.f, 0.f};

    const int srow = lane >> 3;
    const int skb = (lane & 7) ^ srow;

    for (int kc = 0; kc < K; kc += BK) {
        __syncthreads();
#pragma unroll
        for (int i = 0; i < 4; ++i) {
            int c = wave * 4 + i;
            int row = c * 8 + srow;
            gl2lds16(A + (size_t)(tm + row) * K + kc + skb * 8, &As[c * 512]);
            gl2lds16(Bw + (size_t)(tn + row) * K + kc + skb * 8, &Bs[c * 512]);
        }
        __syncthreads();
#pragma unroll
        for (int kk = 0; kk < 2; ++kk) {
            bf16x8 af[4], bfr[4];
            int kb = kk * 4 + (lane >> 4);
#pragma unroll
            for (int t = 0; t < 4; ++t) {
                int r = mo + t * 16 + (lane & 15);
                af[t] = *(const bf16x8*)&As[r * BK + ((kb ^ (r & 7)) << 3)];
                int n = no + t * 16 + (lane & 15);
                bfr[t] = *(const bf16x8*)&Bs[n * BK + ((kb ^ (n & 7)) << 3)];
            }
#pragma unroll
            for (int i = 0; i < 4; ++i)
#pragma unroll
                for (int j = 0; j < 4; ++j)
                    acc[i][j] = __builtin_amdgcn_mfma_f32_16x16x32_bf16(
                        af[i], bfr[j], acc[i][j], 0, 0, 0);
        }
    }

#pragma unroll
    for (int j = 0; j < 4; ++j) {
        int col = tn + no + j * 16 + (lane & 15);
        float bb = bias[col];
#pragma unroll
        for (int i = 0; i < 4; ++i) {
            int row0 = tm + mo + i * 16 + ((lane >> 4) << 2);
            f32x4 v = acc[i][j];
#pragma unroll
            for (int rr = 0; rr < 4; ++rr)
                Cout[(size_t)(row0 + rr) * N + col] = f2bf(fmaxf(v[rr] + bb, 0.f));
        }
    }
}

// ===========================================================================
// GEMM2, 256x256 tile, BK=64, 8 waves (2M x 4N), 4 phases/K-tile, counted
// vmcnt, SINGLE barrier per phase.
// Hazard proof for 1-barrier phases: each phase = [reads(p), stage(p),
// (vmcnt), BARRIER_p, lgkm, MFMA(p)]. Every stage unit targets a region whose
// last ds_read is in an earlier phase, hence before an earlier barrier:
//   ph0: U3(w+1)->other buf rows 64-127/192-255 (read in window w-1)
//   ph1: U0(w+2)->cur B rows 0-127   (read at ph0, before BAR_ph0)
//   ph2: U1(w+2)->cur B rows 128-255 (read at ph0)
//   ph3: U2(w+2)->cur A rows 0-63/128-191 (read at ph0/ph1, before BAR_ph1)
// vmcnt ledger/thread: enter window with 6 outstanding; +2 per phase = 14 at
// ph3; vmcnt(6) drains the 8 oldest = exactly tile w+1, before BAR_ph3 which
// precedes window w+1's first reads. Tail (w>=NT-2): vmcnt(0).
// Epilogue: bias+relu -> LDS (32B-block XOR swizzle, conflict-free) ->
// full-line dwordx4 stores.
// ===========================================================================
__global__ __launch_bounds__(512, 2) void gemm2_8ph(
    const short* __restrict__ A, const short* __restrict__ Bw,
    const float* __restrict__ bias, unsigned short* __restrict__ Cout) {
    constexpr int K = 1024, NT = 16;           // 16 K-tiles of 64
    constexpr unsigned OFF_A0 = 0, OFF_B0 = 16384, OFF_A1 = 32768, OFF_B1 = 49152;
    __shared__ __align__(16) short smem[65536];   // 128 KB

    const int tid = threadIdx.x;
    const int lane = tid & 63;
    const int wave = tid >> 6;      // 0..7
    const int wm = wave >> 2;       // 0..1  -> 128-row half
    const int wn = wave & 3;        // 0..3  -> 64-col quarter
    const int l15 = lane & 15;
    const int quad = lane >> 4;
    const int srow = lane >> 3;
    const int skb8 = ((lane & 7) ^ srow) << 3;

    // bijective XCD swizzle
    const int id = blockIdx.x, nwg = gridDim.x;
    const int xcd = id & 7, lid = id >> 3;
    const int q = nwg >> 3, r = nwg & 7;
    const int wgid = (xcd < r ? xcd * (q + 1) : r * (q + 1) + (xcd - r) * q) + lid;
    const int mt = wgid >> 2, nt = wgid & 3;    // 4 n-tiles (N=1024)
    const size_t Abase = (size_t)(mt * 256) * K;
    const size_t Bbase = (size_t)(nt * 256) * K;

    f32x4 acc[8][4];
#pragma unroll
    for (int m = 0; m < 8; ++m)
#pragma unroll
        for (int n = 0; n < 4; ++n) acc[m][n] = f32x4{0.f, 0.f, 0.f, 0.f};

    auto stage2 = [&](unsigned off, const short* g, size_t rowbase, int kc, int c0, int c1) {
        gl2lds16(g + rowbase + (size_t)(c0 * 8 + srow) * K + kc + skb8, smem + off + c0 * 512);
        gl2lds16(g + rowbase + (size_t)(c1 * 8 + srow) * K + kc + skb8, smem + off + c1 * 512);
    };
    auto stageU = [&](int u, unsigned aOff, unsigned bOff, int kc) {
        if (u == 0)      stage2(bOff, Bw, Bbase, kc, wave * 2, wave * 2 + 1);
        else if (u == 1) stage2(bOff, Bw, Bbase, kc, 16 + wave * 2, 17 + wave * 2);
        else if (u == 2) stage2(aOff, A, Abase, kc, wave, 16 + wave);
        else             stage2(aOff, A, Abase, kc, 8 + wave, 24 + wave);
    };

    // per-lane constant pieces of the swizzled fragment offsets (in shorts)
    // frag offset = row*64 + ((kb ^ (row&7))<<3); row&7 == l15&7
    const unsigned x0 = (unsigned)((quad ^ (l15 & 7)) << 3);          // kk=0
    const unsigned x1 = (unsigned)(((4 + quad) ^ (l15 & 7)) << 3);    // kk=1

    auto window = [&](int w, unsigned caOff, unsigned cbOff, unsigned naOff, unsigned nbOff) {
        const int kc1 = (w + 1) << 6, kc2 = (w + 2) << 6;
        const short* aA = smem + caOff + ((wm << 7) + l15) * 64;
        const short* aB = smem + cbOff + ((wn << 6) + l15) * 64;
        bf16x8 bfr[4][2], af[2][2];

        // ---- phase 0: reads B(all) + A mfrag 0,1 ; stage U3(w+1)->next ; BAR ; MFMA q0
#pragma unroll
        for (int n = 0; n < 4; ++n) {
            bfr[n][0] = ds_read_b128_asm(aB + n * 1024 + x0);
            bfr[n][1] = ds_read_b128_asm(aB + n * 1024 + x1);
        }
#pragma unroll
        for (int mm = 0; mm < 2; ++mm) {
            af[mm][0] = ds_read_b128_asm(aA + mm * 1024 + x0);
            af[mm][1] = ds_read_b128_asm(aA + mm * 1024 + x1);
        }
        if (w + 1 < NT) stageU(3, naOff, nbOff, kc1);
        __builtin_amdgcn_sched_barrier(0);
        __builtin_amdgcn_s_barrier();
        asm volatile("s_waitcnt lgkmcnt(0)" ::: "memory");
        __builtin_amdgcn_sched_barrier(0);
        __builtin_amdgcn_s_setprio(1);
#pragma unroll
        for (int kk = 0; kk < 2; ++kk)
#pragma unroll
            for (int mm = 0; mm < 2; ++mm)
#pragma unroll
                for (int n = 0; n < 4; ++n)
                    acc[mm][n] = __builtin_amdgcn_mfma_f32_16x16x32_bf16(
                        af[mm][kk], bfr[n][kk], acc[mm][n], 0, 0, 0);
        __builtin_amdgcn_s_setprio(0);

        // ---- phases 1..3: reads A mfrag 2p,2p+1 ; stage U(ph-1)(w+2)->cur ; BAR ; MFMA
#pragma unroll
        for (int ph = 1; ph < 4; ++ph) {
#pragma unroll
            for (int mm = 0; mm < 2; ++mm) {
                af[mm][0] = ds_read_b128_asm(aA + (ph * 2 + mm) * 1024 + x0);
                af[mm][1] = ds_read_b128_asm(aA + (ph * 2 + mm) * 1024 + x1);
            }
            if (w + 2 < NT) stageU(ph - 1, caOff, cbOff, kc2);
            if (ph == 3) {
                if (w < NT - 2)
                    asm volatile("s_waitcnt vmcnt(6)" ::: "memory");
                else
                    asm volatile("s_waitcnt vmcnt(0)" ::: "memory");
            }
            __builtin_amdgcn_sched_barrier(0);
            __builtin_amdgcn_s_barrier();
            asm volatile("s_waitcnt lgkmcnt(0)" ::: "memory");
            __builtin_amdgcn_sched_barrier(0);
            __builtin_amdgcn_s_setprio(1);
#pragma unroll
            for (int kk = 0; kk < 2; ++kk)
#pragma unroll
                for (int mm = 0; mm < 2; ++mm)
#pragma unroll
                    for (int n = 0; n < 4; ++n)
                        acc[ph * 2 + mm][n] = __builtin_amdgcn_mfma_f32_16x16x32_bf16(
                            af[mm][kk], bfr[n][kk], acc[ph * 2 + mm][n], 0, 0, 0);
            __builtin_amdgcn_s_setprio(0);
        }
    };

    // ---- prologue: tile0 complete -> buf0; tile1 U0..U2 -> buf1
    stageU(0, OFF_A0, OFF_B0, 0);
    stageU(1, OFF_A0, OFF_B0, 0);
    stageU(2, OFF_A0, OFF_B0, 0);
    stageU(3, OFF_A0, OFF_B0, 0);
    stageU(0, OFF_A1, OFF_B1, 64);
    stageU(1, OFF_A1, OFF_B1, 64);
    stageU(2, OFF_A1, OFF_B1, 64);
    asm volatile("s_waitcnt vmcnt(6)" ::: "memory");
    __builtin_amdgcn_sched_barrier(0);
    __builtin_amdgcn_s_barrier();

#pragma unroll 1
    for (int w = 0; w < NT; w += 2) {
        window(w, OFF_A0, OFF_B0, OFF_A1, OFF_B1);
        window(w + 1, OFF_A1, OFF_B1, OFF_A0, OFF_B0);
    }

    // ---- epilogue: bias+relu -> LDS bf16 (swizzled) -> coalesced store
    __syncthreads();
    unsigned short* cs = (unsigned short*)smem;
#pragma unroll
    for (int n = 0; n < 4; ++n) {
        int colblk = wn * 4 + n;                    // 32B block index 0..15
        int col = (colblk << 4) + l15;
        float bb = bias[nt * 256 + col];
#pragma unroll
        for (int m = 0; m < 8; ++m) {
            int row = (wm << 7) + m * 16 + (quad << 2);
#pragma unroll
            for (int rr = 0; rr < 4; ++rr) {
                int rw = row + rr;
                int sb = colblk ^ ((rw >> 2) & 3);  // bank-group swizzle
                cs[rw * 256 + (sb << 4) + l15] = f2bf(fmaxf(acc[m][n][rr] + bb, 0.f));
            }
        }
    }
    __syncthreads();
    const size_t cbase = (size_t)(mt * 256) * 1024 + nt * 256;
    const int rloc = tid >> 5, cchunk = tid & 31;
#pragma unroll
    for (int rnd = 0; rnd < 16; ++rnd) {
        int rw = rnd * 16 + rloc;
        int blk = cchunk >> 1, half = cchunk & 1;
        int sb = blk ^ ((rw >> 2) & 3);
        short8 v = *(const short8*)&cs[rw * 256 + (sb << 4) + half * 8];
        *(short8*)((unsigned short*)Cout + cbase + (size_t)rw * 1024 + cchunk * 8) = v;
    }
}

// GEMM3 + finalize. Block = 64 rows x 256 cols (full P row-slab), 4 waves.
__global__ __launch_bounds__(256) void gemm3_final(
    const short* __restrict__ H2, const short* __restrict__ W3T,
    const float* __restrict__ b3, const float* __restrict__ x,
    float* __restrict__ out, float* __restrict__ logdet) {
    constexpr int BK = 64, K = 1024;
    __shared__ __align__(16) char raw[40960];
    __shared__ float rowsum[64];
    short* As = (short*)raw;
    short* Bs = (short*)(raw + 8192);
    float* Tbuf = (float*)raw;
    const int tid = threadIdx.x;
    const int lane = tid & 63;
    const int wave = tid >> 6;
    const int tm = blockIdx.x * 64;
    const int srow = lane >> 3;
    const int skb = (lane & 7) ^ srow;
    const int l15 = lane & 15;
    const int quad = lane >> 4;

    if (tid < 64) rowsum[tid] = 0.f;

    f32x4 acc[4][4];
#pragma unroll
    for (int i = 0; i < 4; ++i)
#pragma unroll
        for (int j = 0; j < 4; ++j) acc[i][j] = f32x4{0.f, 0.f, 0.f, 0.f};

    for (int kc = 0; kc < K; kc += BK) {
        __syncthreads();
#pragma unroll
        for (int i = 0; i < 10; ++i) {       // 40 chunks: 8 A + 32 B
            int c = wave * 10 + i;
            if (c < 8) {
                int row = c * 8 + srow;
                gl2lds16(H2 + (size_t)(tm + row) * K + kc + skb * 8, &As[c * 512]);
            } else {
                int row = (c - 8) * 8 + srow;
                gl2lds16(W3T + (size_t)row * K + kc + skb * 8, &Bs[(c - 8) * 512]);
            }
        }
        __syncthreads();
#pragma unroll
        for (int kk = 0; kk < 2; ++kk) {
            int kb = kk * 4 + quad;
            bf16x8 af[4], bfr[4];
#pragma unroll
            for (int mt = 0; mt < 4; ++mt) {
                int r = mt * 16 + l15;
                af[mt] = *(const bf16x8*)&As[r * BK + ((kb ^ (r & 7)) << 3)];
            }
#pragma unroll
            for (int nt = 0; nt < 4; ++nt) {
                int n = wave * 64 + nt * 16 + l15;
                bfr[nt] = *(const bf16x8*)&Bs[n * BK + ((kb ^ (n & 7)) << 3)];
            }
#pragma unroll
            for (int mt = 0; mt < 4; ++mt)
#pragma unroll
                for (int nt = 0; nt < 4; ++nt)
                    acc[mt][nt] = __builtin_amdgcn_mfma_f32_16x16x32_bf16(
                        af[mt], bfr[nt], acc[mt][nt], 0, 0, 0);
        }
    }

    __syncthreads();
    if (wave >= 2) {
#pragma unroll
        for (int nt = 0; nt < 4; ++nt) {
            int col = wave * 64 + nt * 16 + l15;   // 128..255
            float bb = b3[col];
            int cl = col - 128;
#pragma unroll
            for (int mt = 0; mt < 4; ++mt) {
#pragma unroll
                for (int rr = 0; rr < 4; ++rr) {
                    int m = mt * 16 + quad * 4 + rr;
                    Tbuf[m * 132 + cl] = acc[mt][nt][rr] + bb;
                }
            }
        }
    }
    __syncthreads();
    if (wave < 2) {
#pragma unroll
        for (int mt = 0; mt < 4; ++mt) {
#pragma unroll
            for (int rr = 0; rr < 4; ++rr) {
                int m = mt * 16 + quad * 4 + rr;
                int grow = tm + m;
                float s = 0.f;
#pragma unroll
                for (int nt = 0; nt < 4; ++nt) {
                    int j = wave * 64 + nt * 16 + l15;   // 0..127
                    float p = acc[mt][nt][rr] + b3[j];
                    p = fminf(fmaxf(p, -15.f), 15.f);
                    float e2 = __expf(2.f * p);
                    float ls = (e2 - 1.f) / (e2 + 1.f);  // tanh(p)
                    s += ls;
                    float tt = Tbuf[m * 132 + j];
                    float2 xv = *(const float2*)&x[(size_t)grow * 256 + 2 * j];
                    float2 ov;
                    ov.x = xv.x;
                    ov.y = xv.y * __expf(ls) + tt;
                    *(float2*)&out[(size_t)grow * 256 + 2 * j] = ov;
                }
                s += __shfl_xor(s, 1);
                s += __shfl_xor(s, 2);
                s += __shfl_xor(s, 4);
                s += __shfl_xor(s, 8);
                if (l15 == 0) atomicAdd(&rowsum[m], s);
            }
        }
    }
    __syncthreads();
    if (tid < 64) logdet[tm + tid] = rowsum[tid];
}

extern "C" void kernel_launch(void* const* d_in, const int* in_sizes, int n_in,
                              void* d_out, int out_size, void* d_ws, size_t ws_size,
                              hipStream_t stream) {
    const float* x = (const float*)d_in[0];
    const float* cond = (const float*)d_in[1];
    const float* W1 = (const float*)d_in[2];
    const float* b1 = (const float*)d_in[3];
    const float* W2 = (const float*)d_in[4];
    const float* b2 = (const float*)d_in[5];
    const float* Wsp = (const float*)d_in[6];
    const float* bs = (const float*)d_in[7];
    const float* Wtp = (const float*)d_in[8];
    const float* bt = (const float*)d_in[9];

    char* ws = (char*)d_ws;
    short* W1T = (short*)(ws);                          // 1024x256 bf16 = 512 KB
    short* W2T = (short*)(ws + 524288ull);              // 1024x1024 bf16 = 2 MB
    short* W3T = (short*)(ws + 2621440ull);             // 256x1024 bf16 = 512 KB
    float* b3  = (float*)(ws + 3145728ull);             // 1 KB
    const size_t chunk_base = 3149824ull;

    // Per-chunk scratch: H1 = 2048*R, H2 = 2048*R.
    int n_chunks = 1;
    while (n_chunks < 512) {
        size_t rp = (size_t)B_ROWS / n_chunks;
        if (chunk_base + rp * 4096ull <= ws_size) break;
        n_chunks *= 2;
    }
    const size_t RP = (size_t)B_ROWS / n_chunks;

    float* out = (float*)d_out;
    float* logdet = out + (size_t)B_ROWS * D_DIM;

    transpose_bf16<<<(32768 + 255) / 256, 256, 0, stream>>>(W1, W1T, 256, 1024, 32768);
    transpose_bf16<<<(131072 + 255) / 256, 256, 0, stream>>>(W2, W2T, 1024, 1024, 131072);
    transpose_bf16<<<(16384 + 255) / 256, 256, 0, stream>>>(Wsp, W3T, 1024, 128, 16384);
    transpose_bf16<<<(16384 + 255) / 256, 256, 0, stream>>>(Wtp, W3T + 131072, 1024, 128, 16384);
    prep_b3<<<1, 256, 0, stream>>>(bs, bt, b3);

    for (int c = 0; c < n_chunks; ++c) {
        const size_t r0 = (size_t)c * RP;
        short* H1 = (short*)(ws + chunk_base);
        short* H2 = (short*)(ws + chunk_base + 2048ull * RP);
        const int mtiles = (int)(RP / 128);

        gemm1_fused<<<mtiles * 8, 256, 0, stream>>>(
            x + r0 * D_DIM, cond + r0 * C_DIM, W1T, b1, (unsigned short*)H1, mtiles);
        if ((RP & 255) == 0) {
            gemm2_8ph<<<(int)(RP / 256) * 4, 512, 0, stream>>>(
                H1, W2T, b2, (unsigned short*)H2);
        } else {
            gemm_tn<<<mtiles * 8, 256, 0, stream>>>(
                H1, W2T, b2, (unsigned short*)H2, mtiles, H_DIM, H_DIM);
        }
        gemm3_final<<<(int)(RP / 64), 256, 0, stream>>>(
            H2, W3T, b3, x + r0 * D_DIM, out + r0 * D_DIM, logdet + r0);
    }
}

// Round 5
// 460.088 us; speedup vs baseline: 1.1046x; 1.0245x over previous
//
#include <hip/hip_runtime.h>
#include <hip/hip_bf16.h>
#include <math.h>

#define B_ROWS 65536
#define D_DIM 256
#define C_DIM 128
#define H_DIM 1024

typedef __bf16 bf16x8 __attribute__((ext_vector_type(8)));
typedef float f32x4 __attribute__((ext_vector_type(4)));
typedef short short8 __attribute__((ext_vector_type(8)));

__device__ __forceinline__ unsigned short f2bf(float f) {
    unsigned int u = __float_as_uint(f);
    u += 0x7fffu + ((u >> 16) & 1u);
    return (unsigned short)(u >> 16);
}

__device__ __forceinline__ void gl2lds16(const void* g, void* l) {
    __builtin_amdgcn_global_load_lds(
        (const __attribute__((address_space(1))) unsigned int*)g,
        (__attribute__((address_space(3))) unsigned int*)l, 16, 0, 0);
}

// Opaque LDS read via a proper address_space(3) pointer (32-bit LDS address,
// no flat-aperture truncation). Compiler does not model the dependency on
// outstanding global_load_lds, so it cannot insert a conservative vmcnt(0)
// drain; correctness comes from our explicit barriers + counted vmcnt.
__device__ __forceinline__ bf16x8 ds_read_b128_asm(const short* p) {
    bf16x8 r;
    asm volatile("ds_read_b128 %0, %1"
                 : "=v"(r)
                 : "v"((const __attribute__((address_space(3))) short*)p));
    return r;
}

// XCD-aware swizzle: all 8 N-tiles of one M-tile land on the same XCD.
__device__ __forceinline__ void swizzle_mn(int id, int mtiles, int& m, int& n) {
    if ((mtiles & 7) == 0) {
        int g = id >> 6, r = id & 63;
        m = g * 8 + (r & 7);
        n = r >> 3;
    } else {
        m = id >> 3;
        n = id & 7;
    }
}

// dst[n*R + k] = bf16(src[k*C + n]); src is R x C row-major, dst N x K
__global__ void transpose_bf16(const float* __restrict__ src, short* __restrict__ dst,
                               int R, int C, int total) {
    int tid = blockIdx.x * 256 + threadIdx.x;
    if (tid >= total) return;
    int per = R >> 3;
    int n = tid / per;
    int k0 = (tid - n * per) << 3;
    short8 o;
#pragma unroll
    for (int j = 0; j < 8; ++j) o[j] = (short)f2bf(src[(size_t)(k0 + j) * C + n]);
    *(short8*)&dst[(size_t)n * R + k0] = o;
}

__global__ void prep_b3(const float* __restrict__ bs, const float* __restrict__ bt,
                        float* __restrict__ b3) {
    int i = threadIdx.x;
    b3[i] = (i < 128) ? bs[i] : bt[i - 128];
}

// A-prep: A[m][0..127] = bf16(x[m][2k]), A[m][128..255] = bf16(cond[m][k]).
// Memory-bound; 32 threads per row, 8 rows per 256-thread block.
__global__ __launch_bounds__(256) void prep_a(
    const float* __restrict__ x, const float* __restrict__ cond,
    short* __restrict__ A) {
    int t = blockIdx.x * 256 + threadIdx.x;
    int m = t >> 5, seg = t & 31;
    short8 o;
    if (seg < 16) {
        const float4* p = (const float4*)(x + (size_t)m * 256 + seg * 16);
        float4 a = p[0], b = p[1], c = p[2], d = p[3];
        o[0] = (short)f2bf(a.x); o[1] = (short)f2bf(a.z);
        o[2] = (short)f2bf(b.x); o[3] = (short)f2bf(b.z);
        o[4] = (short)f2bf(c.x); o[5] = (short)f2bf(c.z);
        o[6] = (short)f2bf(d.x); o[7] = (short)f2bf(d.z);
    } else {
        const float4* p = (const float4*)(cond + (size_t)m * 128 + (seg - 16) * 8);
        float4 a = p[0], b = p[1];
        o[0] = (short)f2bf(a.x); o[1] = (short)f2bf(a.y);
        o[2] = (short)f2bf(a.z); o[3] = (short)f2bf(a.w);
        o[4] = (short)f2bf(b.x); o[5] = (short)f2bf(b.y);
        o[6] = (short)f2bf(b.z); o[7] = (short)f2bf(b.w);
    }
    *(short8*)&A[(size_t)m * 256 + seg * 8] = o;
}

// Generic fallback GEMM (128x128 tile), used only if RP % 256 != 0.
__global__ __launch_bounds__(256) void gemm_tn(
    const short* __restrict__ A, const short* __restrict__ Bw,
    const float* __restrict__ bias, unsigned short* __restrict__ Cout,
    int mtiles, int N, int K) {
    constexpr int BK = 64;
    __shared__ __align__(16) short As[128 * BK];
    __shared__ __align__(16) short Bs[128 * BK];
    const int tid = threadIdx.x;
    const int lane = tid & 63;
    const int wave = tid >> 6;
    int mt, nt;
    swizzle_mn(blockIdx.x, mtiles, mt, nt);
    const int tm = mt * 128, tn = nt * 128;
    const int mo = (wave >> 1) * 64;
    const int no = (wave & 1) * 64;

    f32x4 acc[4][4];
#pragma unroll
    for (int i = 0; i < 4; ++i)
#pragma unroll
        for (int j = 0; j < 4; ++j) acc[i][j] = f32x4{0.f, 0.f, 0.f, 0.f};

    const int srow = lane >> 3;
    const int skb = (lane & 7) ^ srow;

    for (int kc = 0; kc < K; kc += BK) {
        __syncthreads();
#pragma unroll
        for (int i = 0; i < 4; ++i) {
            int c = wave * 4 + i;
            int row = c * 8 + srow;
            gl2lds16(A + (size_t)(tm + row) * K + kc + skb * 8, &As[c * 512]);
            gl2lds16(Bw + (size_t)(tn + row) * K + kc + skb * 8, &Bs[c * 512]);
        }
        __syncthreads();
#pragma unroll
        for (int kk = 0; kk < 2; ++kk) {
            bf16x8 af[4], bfr[4];
            int kb = kk * 4 + (lane >> 4);
#pragma unroll
            for (int t = 0; t < 4; ++t) {
                int r = mo + t * 16 + (lane & 15);
                af[t] = *(const bf16x8*)&As[r * BK + ((kb ^ (r & 7)) << 3)];
                int n = no + t * 16 + (lane & 15);
                bfr[t] = *(const bf16x8*)&Bs[n * BK + ((kb ^ (n & 7)) << 3)];
            }
#pragma unroll
            for (int i = 0; i < 4; ++i)
#pragma unroll
                for (int j = 0; j < 4; ++j)
                    acc[i][j] = __builtin_amdgcn_mfma_f32_16x16x32_bf16(
                        af[i], bfr[j], acc[i][j], 0, 0, 0);
        }
    }

#pragma unroll
    for (int j = 0; j < 4; ++j) {
        int col = tn + no + j * 16 + (lane & 15);
        float bb = bias[col];
#pragma unroll
        for (int i = 0; i < 4; ++i) {
            int row0 = tm + mo + i * 16 + ((lane >> 4) << 2);
            f32x4 v = acc[i][j];
#pragma unroll
            for (int rr = 0; rr < 4; ++rr)
                Cout[(size_t)(row0 + rr) * N + col] = f2bf(fmaxf(v[rr] + bb, 0.f));
        }
    }
}

// ===========================================================================
// Pipelined GEMM (templated K), 256x256 tile, BK=64, 8 waves (2M x 4N),
// 4 phases/K-tile, counted vmcnt, single barrier per phase.
// Output is always M x 1024 with relu(. + bias) bf16.
// Hazard proof: each phase = [reads(p), stage(p), (vmcnt), BARRIER_p, lgkm,
// MFMA(p)]. Every stage unit targets a region whose last ds_read is in an
// earlier phase, hence before an earlier barrier:
//   ph0: U3(w+1)->other buf rows 64-127/192-255 (read in window w-1)
//   ph1: U0(w+2)->cur B rows 0-127   (read at ph0, before BAR_ph0)
//   ph2: U1(w+2)->cur B rows 128-255 (read at ph0)
//   ph3: U2(w+2)->cur A rows 0-63/128-191 (read at ph0/ph1, before BAR_ph1)
// vmcnt ledger/thread: enter window with 6 outstanding; +2 per phase = 14 at
// ph3; vmcnt(6) drains the 8 oldest = exactly tile w+1, before BAR_ph3 which
// precedes window w+1's first reads. Tail (w>=NT-2): vmcnt(0), stage guards
// off. Verified for NT=16 (K=1024) and NT=4 (K=256).
// Epilogue: bias+relu -> LDS (32B-block XOR swizzle) -> full-line stores.
// ===========================================================================
template<int K>
__global__ __launch_bounds__(512, 2) void gemm2_8ph(
    const short* __restrict__ A, const short* __restrict__ Bw,
    const float* __restrict__ bias, unsigned short* __restrict__ Cout) {
    constexpr int NT = K / 64;
    constexpr unsigned OFF_A0 = 0, OFF_B0 = 16384, OFF_A1 = 32768, OFF_B1 = 49152;
    __shared__ __align__(16) short smem[65536];   // 128 KB

    const int tid = threadIdx.x;
    const int lane = tid & 63;
    const int wave = tid >> 6;      // 0..7
    const int wm = wave >> 2;       // 0..1  -> 128-row half
    const int wn = wave & 3;        // 0..3  -> 64-col quarter
    const int l15 = lane & 15;
    const int quad = lane >> 4;
    const int srow = lane >> 3;
    const int skb8 = ((lane & 7) ^ srow) << 3;

    // bijective XCD swizzle
    const int id = blockIdx.x, nwg = gridDim.x;
    const int xcd = id & 7, lid = id >> 3;
    const int q = nwg >> 3, r = nwg & 7;
    const int wgid = (xcd < r ? xcd * (q + 1) : r * (q + 1) + (xcd - r) * q) + lid;
    const int mt = wgid >> 2, nt = wgid & 3;    // 4 n-tiles (N=1024)
    const size_t Abase = (size_t)(mt * 256) * K;
    const size_t Bbase = (size_t)(nt * 256) * K;

    f32x4 acc[8][4];
#pragma unroll
    for (int m = 0; m < 8; ++m)
#pragma unroll
        for (int n = 0; n < 4; ++n) acc[m][n] = f32x4{0.f, 0.f, 0.f, 0.f};

    auto stage2 = [&](unsigned off, const short* g, size_t rowbase, int kc, int c0, int c1) {
        gl2lds16(g + rowbase + (size_t)(c0 * 8 + srow) * K + kc + skb8, smem + off + c0 * 512);
        gl2lds16(g + rowbase + (size_t)(c1 * 8 + srow) * K + kc + skb8, smem + off + c1 * 512);
    };
    auto stageU = [&](int u, unsigned aOff, unsigned bOff, int kc) {
        if (u == 0)      stage2(bOff, Bw, Bbase, kc, wave * 2, wave * 2 + 1);
        else if (u == 1) stage2(bOff, Bw, Bbase, kc, 16 + wave * 2, 17 + wave * 2);
        else if (u == 2) stage2(aOff, A, Abase, kc, wave, 16 + wave);
        else             stage2(aOff, A, Abase, kc, 8 + wave, 24 + wave);
    };

    // per-lane constant pieces of the swizzled fragment offsets (in shorts)
    // frag offset = row*64 + ((kb ^ (row&7))<<3); row&7 == l15&7
    const unsigned x0 = (unsigned)((quad ^ (l15 & 7)) << 3);          // kk=0
    const unsigned x1 = (unsigned)(((4 + quad) ^ (l15 & 7)) << 3);    // kk=1

    auto window = [&](int w, unsigned caOff, unsigned cbOff, unsigned naOff, unsigned nbOff) {
        const int kc1 = (w + 1) << 6, kc2 = (w + 2) << 6;
        const short* aA = smem + caOff + ((wm << 7) + l15) * 64;
        const short* aB = smem + cbOff + ((wn << 6) + l15) * 64;
        bf16x8 bfr[4][2], af[2][2];

        // ---- phase 0: reads B(all) + A mfrag 0,1 ; stage U3(w+1)->next ; BAR ; MFMA q0
#pragma unroll
        for (int n = 0; n < 4; ++n) {
            bfr[n][0] = ds_read_b128_asm(aB + n * 1024 + x0);
            bfr[n][1] = ds_read_b128_asm(aB + n * 1024 + x1);
        }
#pragma unroll
        for (int mm = 0; mm < 2; ++mm) {
            af[mm][0] = ds_read_b128_asm(aA + mm * 1024 + x0);
            af[mm][1] = ds_read_b128_asm(aA + mm * 1024 + x1);
        }
        if (w + 1 < NT) stageU(3, naOff, nbOff, kc1);
        __builtin_amdgcn_sched_barrier(0);
        __builtin_amdgcn_s_barrier();
        asm volatile("s_waitcnt lgkmcnt(0)" ::: "memory");
        __builtin_amdgcn_sched_barrier(0);
        __builtin_amdgcn_s_setprio(1);
#pragma unroll
        for (int kk = 0; kk < 2; ++kk)
#pragma unroll
            for (int mm = 0; mm < 2; ++mm)
#pragma unroll
                for (int n = 0; n < 4; ++n)
                    acc[mm][n] = __builtin_amdgcn_mfma_f32_16x16x32_bf16(
                        af[mm][kk], bfr[n][kk], acc[mm][n], 0, 0, 0);
        __builtin_amdgcn_s_setprio(0);

        // ---- phases 1..3: reads A mfrag 2p,2p+1 ; stage U(ph-1)(w+2)->cur ; BAR ; MFMA
#pragma unroll
        for (int ph = 1; ph < 4; ++ph) {
#pragma unroll
            for (int mm = 0; mm < 2; ++mm) {
                af[mm][0] = ds_read_b128_asm(aA + (ph * 2 + mm) * 1024 + x0);
                af[mm][1] = ds_read_b128_asm(aA + (ph * 2 + mm) * 1024 + x1);
            }
            if (w + 2 < NT) stageU(ph - 1, caOff, cbOff, kc2);
            if (ph == 3) {
                if (w < NT - 2)
                    asm volatile("s_waitcnt vmcnt(6)" ::: "memory");
                else
                    asm volatile("s_waitcnt vmcnt(0)" ::: "memory");
            }
            __builtin_amdgcn_sched_barrier(0);
            __builtin_amdgcn_s_barrier();
            asm volatile("s_waitcnt lgkmcnt(0)" ::: "memory");
            __builtin_amdgcn_sched_barrier(0);
            __builtin_amdgcn_s_setprio(1);
#pragma unroll
            for (int kk = 0; kk < 2; ++kk)
#pragma unroll
                for (int mm = 0; mm < 2; ++mm)
#pragma unroll
                    for (int n = 0; n < 4; ++n)
                        acc[ph * 2 + mm][n] = __builtin_amdgcn_mfma_f32_16x16x32_bf16(
                            af[mm][kk], bfr[n][kk], acc[ph * 2 + mm][n], 0, 0, 0);
            __builtin_amdgcn_s_setprio(0);
        }
    };

    // ---- prologue: tile0 complete -> buf0; tile1 U0..U2 -> buf1
    stageU(0, OFF_A0, OFF_B0, 0);
    stageU(1, OFF_A0, OFF_B0, 0);
    stageU(2, OFF_A0, OFF_B0, 0);
    stageU(3, OFF_A0, OFF_B0, 0);
    stageU(0, OFF_A1, OFF_B1, 64);
    stageU(1, OFF_A1, OFF_B1, 64);
    stageU(2, OFF_A1, OFF_B1, 64);
    asm volatile("s_waitcnt vmcnt(6)" ::: "memory");
    __builtin_amdgcn_sched_barrier(0);
    __builtin_amdgcn_s_barrier();

#pragma unroll 1
    for (int w = 0; w < NT; w += 2) {
        window(w, OFF_A0, OFF_B0, OFF_A1, OFF_B1);
        window(w + 1, OFF_A1, OFF_B1, OFF_A0, OFF_B0);
    }

    // ---- epilogue: bias+relu -> LDS bf16 (swizzled) -> coalesced store
    __syncthreads();
    unsigned short* cs = (unsigned short*)smem;
#pragma unroll
    for (int n = 0; n < 4; ++n) {
        int colblk = wn * 4 + n;                    // 32B block index 0..15
        int col = (colblk << 4) + l15;
        float bb = bias[nt * 256 + col];
#pragma unroll
        for (int m = 0; m < 8; ++m) {
            int row = (wm << 7) + m * 16 + (quad << 2);
#pragma unroll
            for (int rr = 0; rr < 4; ++rr) {
                int rw = row + rr;
                int sb = colblk ^ ((rw >> 2) & 3);  // bank-group swizzle
                cs[rw * 256 + (sb << 4) + l15] = f2bf(fmaxf(acc[m][n][rr] + bb, 0.f));
            }
        }
    }
    __syncthreads();
    const size_t cbase = (size_t)(mt * 256) * 1024 + nt * 256;
    const int rloc = tid >> 5, cchunk = tid & 31;
#pragma unroll
    for (int rnd = 0; rnd < 16; ++rnd) {
        int rw = rnd * 16 + rloc;
        int blk = cchunk >> 1, half = cchunk & 1;
        int sb = blk ^ ((rw >> 2) & 3);
        short8 v = *(const short8*)&cs[rw * 256 + (sb << 4) + half * 8];
        *(short8*)((unsigned short*)Cout + cbase + (size_t)rw * 1024 + cchunk * 8) = v;
    }
}

// GEMM3 + finalize. Block = 64 rows x 256 cols (full P row-slab), 4 waves.
__global__ __launch_bounds__(256) void gemm3_final(
    const short* __restrict__ H2, const short* __restrict__ W3T,
    const float* __restrict__ b3, const float* __restrict__ x,
    float* __restrict__ out, float* __restrict__ logdet) {
    constexpr int BK = 64, K = 1024;
    __shared__ __align__(16) char raw[40960];
    __shared__ float rowsum[64];
    short* As = (short*)raw;
    short* Bs = (short*)(raw + 8192);
    float* Tbuf = (float*)raw;
    const int tid = threadIdx.x;
    const int lane = tid & 63;
    const int wave = tid >> 6;
    const int tm = blockIdx.x * 64;
    const int srow = lane >> 3;
    const int skb = (lane & 7) ^ srow;
    const int l15 = lane & 15;
    const int quad = lane >> 4;

    if (tid < 64) rowsum[tid] = 0.f;

    f32x4 acc[4][4];
#pragma unroll
    for (int i = 0; i < 4; ++i)
#pragma unroll
        for (int j = 0; j < 4; ++j) acc[i][j] = f32x4{0.f, 0.f, 0.f, 0.f};

    for (int kc = 0; kc < K; kc += BK) {
        __syncthreads();
#pragma unroll
        for (int i = 0; i < 10; ++i) {       // 40 chunks: 8 A + 32 B
            int c = wave * 10 + i;
            if (c < 8) {
                int row = c * 8 + srow;
                gl2lds16(H2 + (size_t)(tm + row) * K + kc + skb * 8, &As[c * 512]);
            } else {
                int row = (c - 8) * 8 + srow;
                gl2lds16(W3T + (size_t)row * K + kc + skb * 8, &Bs[(c - 8) * 512]);
            }
        }
        __syncthreads();
#pragma unroll
        for (int kk = 0; kk < 2; ++kk) {
            int kb = kk * 4 + quad;
            bf16x8 af[4], bfr[4];
#pragma unroll
            for (int mt = 0; mt < 4; ++mt) {
                int r = mt * 16 + l15;
                af[mt] = *(const bf16x8*)&As[r * BK + ((kb ^ (r & 7)) << 3)];
            }
#pragma unroll
            for (int nt = 0; nt < 4; ++nt) {
                int n = wave * 64 + nt * 16 + l15;
                bfr[nt] = *(const bf16x8*)&Bs[n * BK + ((kb ^ (n & 7)) << 3)];
            }
#pragma unroll
            for (int mt = 0; mt < 4; ++mt)
#pragma unroll
                for (int nt = 0; nt < 4; ++nt)
                    acc[mt][nt] = __builtin_amdgcn_mfma_f32_16x16x32_bf16(
                        af[mt], bfr[nt], acc[mt][nt], 0, 0, 0);
        }
    }

    __syncthreads();
    if (wave >= 2) {
#pragma unroll
        for (int nt = 0; nt < 4; ++nt) {
            int col = wave * 64 + nt * 16 + l15;   // 128..255
            float bb = b3[col];
            int cl = col - 128;
#pragma unroll
            for (int mt = 0; mt < 4; ++mt) {
#pragma unroll
                for (int rr = 0; rr < 4; ++rr) {
                    int m = mt * 16 + quad * 4 + rr;
                    Tbuf[m * 132 + cl] = acc[mt][nt][rr] + bb;
                }
            }
        }
    }
    __syncthreads();
    if (wave < 2) {
#pragma unroll
        for (int mt = 0; mt < 4; ++mt) {
#pragma unroll
            for (int rr = 0; rr < 4; ++rr) {
                int m = mt * 16 + quad * 4 + rr;
                int grow = tm + m;
                float s = 0.f;
#pragma unroll
                for (int nt = 0; nt < 4; ++nt) {
                    int j = wave * 64 + nt * 16 + l15;   // 0..127
                    float p = acc[mt][nt][rr] + b3[j];
                    p = fminf(fmaxf(p, -15.f), 15.f);
                    float e2 = __expf(2.f * p);
                    float ls = (e2 - 1.f) / (e2 + 1.f);  // tanh(p)
                    s += ls;
                    float tt = Tbuf[m * 132 + j];
                    float2 xv = *(const float2*)&x[(size_t)grow * 256 + 2 * j];
                    float2 ov;
                    ov.x = xv.x;
                    ov.y = xv.y * __expf(ls) + tt;
                    *(float2*)&out[(size_t)grow * 256 + 2 * j] = ov;
                }
                s += __shfl_xor(s, 1);
                s += __shfl_xor(s, 2);
                s += __shfl_xor(s, 4);
                s += __shfl_xor(s, 8);
                if (l15 == 0) atomicAdd(&rowsum[m], s);
            }
        }
    }
    __syncthreads();
    if (tid < 64) logdet[tm + tid] = rowsum[tid];
}

extern "C" void kernel_launch(void* const* d_in, const int* in_sizes, int n_in,
                              void* d_out, int out_size, void* d_ws, size_t ws_size,
                              hipStream_t stream) {
    const float* x = (const float*)d_in[0];
    const float* cond = (const float*)d_in[1];
    const float* W1 = (const float*)d_in[2];
    const float* b1 = (const float*)d_in[3];
    const float* W2 = (const float*)d_in[4];
    const float* b2 = (const float*)d_in[5];
    const float* Wsp = (const float*)d_in[6];
    const float* bs = (const float*)d_in[7];
    const float* Wtp = (const float*)d_in[8];
    const float* bt = (const float*)d_in[9];

    char* ws = (char*)d_ws;
    short* W1T = (short*)(ws);                          // 1024x256 bf16 = 512 KB
    short* W2T = (short*)(ws + 524288ull);              // 1024x1024 bf16 = 2 MB
    short* W3T = (short*)(ws + 2621440ull);             // 256x1024 bf16 = 512 KB
    float* b3  = (float*)(ws + 3145728ull);             // 1 KB
    short* Aprep = (short*)(ws + 3149824ull);           // 65536x256 bf16 = 32 MB
    const size_t chunk_base = 3149824ull + 33554432ull;

    // Per-chunk scratch: H1 = 2048*R, H2 = 2048*R.
    int n_chunks = 1;
    while (n_chunks < 512) {
        size_t rp = (size_t)B_ROWS / n_chunks;
        if (chunk_base + rp * 4096ull <= ws_size) break;
        n_chunks *= 2;
    }
    const size_t RP = (size_t)B_ROWS / n_chunks;

    float* out = (float*)d_out;
    float* logdet = out + (size_t)B_ROWS * D_DIM;

    transpose_bf16<<<(32768 + 255) / 256, 256, 0, stream>>>(W1, W1T, 256, 1024, 32768);
    transpose_bf16<<<(131072 + 255) / 256, 256, 0, stream>>>(W2, W2T, 1024, 1024, 131072);
    transpose_bf16<<<(16384 + 255) / 256, 256, 0, stream>>>(Wsp, W3T, 1024, 128, 16384);
    transpose_bf16<<<(16384 + 255) / 256, 256, 0, stream>>>(Wtp, W3T + 131072, 1024, 128, 16384);
    prep_b3<<<1, 256, 0, stream>>>(bs, bt, b3);
    prep_a<<<B_ROWS * 32 / 256, 256, 0, stream>>>(x, cond, Aprep);

    for (int c = 0; c < n_chunks; ++c) {
        const size_t r0 = (size_t)c * RP;
        short* H1 = (short*)(ws + chunk_base);
        short* H2 = (short*)(ws + chunk_base + 2048ull * RP);
        const int mtiles = (int)(RP / 128);

        if ((RP & 255) == 0) {
            gemm2_8ph<256><<<(int)(RP / 256) * 4, 512, 0, stream>>>(
                Aprep + r0 * 256, W1T, b1, (unsigned short*)H1);
            gemm2_8ph<1024><<<(int)(RP / 256) * 4, 512, 0, stream>>>(
                H1, W2T, b2, (unsigned short*)H2);
        } else {
            gemm_tn<<<mtiles * 8, 256, 0, stream>>>(
                Aprep + r0 * 256, W1T, b1, (unsigned short*)H1, mtiles, H_DIM, 256);
            gemm_tn<<<mtiles * 8, 256, 0, stream>>>(
                H1, W2T, b2, (unsigned short*)H2, mtiles, H_DIM, H_DIM);
        }
        gemm3_final<<<(int)(RP / 64), 256, 0, stream>>>(
            H2, W3T, b3, x + r0 * D_DIM, out + r0 * D_DIM, logdet + r0);
    }
}

// Round 6
// 458.558 us; speedup vs baseline: 1.1083x; 1.0033x over previous
//
#include <hip/hip_runtime.h>
#include <hip/hip_bf16.h>
#include <math.h>

#define B_ROWS 65536
#define D_DIM 256
#define C_DIM 128
#define H_DIM 1024

typedef __bf16 bf16x8 __attribute__((ext_vector_type(8)));
typedef float f32x4 __attribute__((ext_vector_type(4)));
typedef short short8 __attribute__((ext_vector_type(8)));

__device__ __forceinline__ unsigned short f2bf(float f) {
    unsigned int u = __float_as_uint(f);
    u += 0x7fffu + ((u >> 16) & 1u);
    return (unsigned short)(u >> 16);
}

__device__ __forceinline__ void gl2lds16(const void* g, void* l) {
    __builtin_amdgcn_global_load_lds(
        (const __attribute__((address_space(1))) unsigned int*)g,
        (__attribute__((address_space(3))) unsigned int*)l, 16, 0, 0);
}

// Opaque LDS read via a proper address_space(3) pointer. Compiler cannot see
// the dependency on outstanding global_load_lds -> no conservative vmcnt(0)
// drains; correctness comes from explicit barriers + counted vmcnt.
__device__ __forceinline__ bf16x8 ds_read_b128_asm(const short* p) {
    bf16x8 r;
    asm volatile("ds_read_b128 %0, %1"
                 : "=v"(r)
                 : "v"((const __attribute__((address_space(3))) short*)p));
    return r;
}

// XCD-aware swizzle: all 8 N-tiles of one M-tile land on the same XCD.
__device__ __forceinline__ void swizzle_mn(int id, int mtiles, int& m, int& n) {
    if ((mtiles & 7) == 0) {
        int g = id >> 6, r = id & 63;
        m = g * 8 + (r & 7);
        n = r >> 3;
    } else {
        m = id >> 3;
        n = id & 7;
    }
}

// dst[n*R + k] = bf16(src[k*C + n]); src is R x C row-major, dst N x K
__global__ void transpose_bf16(const float* __restrict__ src, short* __restrict__ dst,
                               int R, int C, int total) {
    int tid = blockIdx.x * 256 + threadIdx.x;
    if (tid >= total) return;
    int per = R >> 3;
    int n = tid / per;
    int k0 = (tid - n * per) << 3;
    short8 o;
#pragma unroll
    for (int j = 0; j < 8; ++j) o[j] = (short)f2bf(src[(size_t)(k0 + j) * C + n]);
    *(short8*)&dst[(size_t)n * R + k0] = o;
}

__global__ void prep_b3(const float* __restrict__ bs, const float* __restrict__ bt,
                        float* __restrict__ b3) {
    int i = threadIdx.x;
    b3[i] = (i < 128) ? bs[i] : bt[i - 128];
}

// A-prep: A[m][0..127] = bf16(x[m][2k]), A[m][128..255] = bf16(cond[m][k]).
__global__ __launch_bounds__(256) void prep_a(
    const float* __restrict__ x, const float* __restrict__ cond,
    short* __restrict__ A) {
    int t = blockIdx.x * 256 + threadIdx.x;
    int m = t >> 5, seg = t & 31;
    short8 o;
    if (seg < 16) {
        const float4* p = (const float4*)(x + (size_t)m * 256 + seg * 16);
        float4 a = p[0], b = p[1], c = p[2], d = p[3];
        o[0] = (short)f2bf(a.x); o[1] = (short)f2bf(a.z);
        o[2] = (short)f2bf(b.x); o[3] = (short)f2bf(b.z);
        o[4] = (short)f2bf(c.x); o[5] = (short)f2bf(c.z);
        o[6] = (short)f2bf(d.x); o[7] = (short)f2bf(d.z);
    } else {
        const float4* p = (const float4*)(cond + (size_t)m * 128 + (seg - 16) * 8);
        float4 a = p[0], b = p[1];
        o[0] = (short)f2bf(a.x); o[1] = (short)f2bf(a.y);
        o[2] = (short)f2bf(a.z); o[3] = (short)f2bf(a.w);
        o[4] = (short)f2bf(b.x); o[5] = (short)f2bf(b.y);
        o[6] = (short)f2bf(b.z); o[7] = (short)f2bf(b.w);
    }
    *(short8*)&A[(size_t)m * 256 + seg * 8] = o;
}

// Generic fallback GEMM (128x128 tile), used only if RP % 256 != 0.
__global__ __launch_bounds__(256) void gemm_tn(
    const short* __restrict__ A, const short* __restrict__ Bw,
    const float* __restrict__ bias, unsigned short* __restrict__ Cout,
    int mtiles, int N, int K) {
    constexpr int BK = 64;
    __shared__ __align__(16) short As[128 * BK];
    __shared__ __align__(16) short Bs[128 * BK];
    const int tid = threadIdx.x;
    const int lane = tid & 63;
    const int wave = tid >> 6;
    int mt, nt;
    swizzle_mn(blockIdx.x, mtiles, mt, nt);
    const int tm = mt * 128, tn = nt * 128;
    const int mo = (wave >> 1) * 64;
    const int no = (wave & 1) * 64;

    f32x4 acc[4][4];
#pragma unroll
    for (int i = 0; i < 4; ++i)
#pragma unroll
        for (int j = 0; j < 4; ++j) acc[i][j] = f32x4{0.f, 0.f, 0.f, 0.f};

    const int srow = lane >> 3;
    const int skb = (lane & 7) ^ srow;

    for (int kc = 0; kc < K; kc += BK) {
        __syncthreads();
#pragma unroll
        for (int i = 0; i < 4; ++i) {
            int c = wave * 4 + i;
            int row = c * 8 + srow;
            gl2lds16(A + (size_t)(tm + row) * K + kc + skb * 8, &As[c * 512]);
            gl2lds16(Bw + (size_t)(tn + row) * K + kc + skb * 8, &Bs[c * 512]);
        }
        __syncthreads();
#pragma unroll
        for (int kk = 0; kk < 2; ++kk) {
            bf16x8 af[4], bfr[4];
            int kb = kk * 4 + (lane >> 4);
#pragma unroll
            for (int t = 0; t < 4; ++t) {
                int r = mo + t * 16 + (lane & 15);
                af[t] = *(const bf16x8*)&As[r * BK + ((kb ^ (r & 7)) << 3)];
                int n = no + t * 16 + (lane & 15);
                bfr[t] = *(const bf16x8*)&Bs[n * BK + ((kb ^ (n & 7)) << 3)];
            }
#pragma unroll
            for (int i = 0; i < 4; ++i)
#pragma unroll
                for (int j = 0; j < 4; ++j)
                    acc[i][j] = __builtin_amdgcn_mfma_f32_16x16x32_bf16(
                        af[i], bfr[j], acc[i][j], 0, 0, 0);
        }
    }

#pragma unroll
    for (int j = 0; j < 4; ++j) {
        int col = tn + no + j * 16 + (lane & 15);
        float bb = bias[col];
#pragma unroll
        for (int i = 0; i < 4; ++i) {
            int row0 = tm + mo + i * 16 + ((lane >> 4) << 2);
            f32x4 v = acc[i][j];
#pragma unroll
            for (int rr = 0; rr < 4; ++rr)
                Cout[(size_t)(row0 + rr) * N + col] = f2bf(fmaxf(v[rr] + bb, 0.f));
        }
    }
}

// ===========================================================================
// Pipelined GEMM (templated K), 256x256 tile, BK=64, 8 waves (2M x 4N).
// Slot-pipelined: per slot [vmcnt? -> BARRIER -> stage -> lgkmcnt(0) ->
// MFMA(frags read LAST slot) -> ds_read(frags for NEXT slot)].
// The ds_reads issue after the MFMA cluster into the SAME registers (MFMA
// reads sources at issue; LDS write-back is >=64cyc later) and are serviced
// while the matrix pipe drains -> LDS and MFMA overlap, no extra VGPRs.
// Slot 0's MFMA uses zero-initialized frags (adds 0; keeps code uniform).
//
// Stage schedule (unchanged): ph0 -> U3(w+1) into other buf; ph1..3 ->
// U(ph-1)(w+2) into cur buf. U0=B rows0-127, U1=B rows128-255,
// U2=A rows{0-63,128-191}, U3=A rows{64-127,192-255}. Anti-deps: every stage
// is issued after a barrier that follows the last conflicting read's issue;
// read queued-at-LDS before staged write returns from HBM.
//
// vmcnt ledger (stage now AFTER the slot barrier): vmcnt(6)=keep-3-units at
// EVERY ODD slot, pre-barrier. Stages S(4w)=U3(w+1), S(4w+1)=U0(w+2),
// S(4w+2)=U1(w+2), S(4w+3)=U2(w+2). Drain at pre-BAR slot s keeps
// S(s-3..s-1), so: slot 4w+3 drains through U2(w+1) (deadline BAR 4w+4 for
// U0-2(w+1): met); slot 4w+5 drains through U0(w+2) >= U3(w+1) (deadline
// BAR 4w+6: met). Prologue: 7 units, vmcnt(6) leaves U0-2(1). Tail
// (w>=NT-2): vmcnt(0). Verified NT=16 and NT=4.
// ===========================================================================
template<int K>
__global__ __launch_bounds__(512, 2) void gemm2_8ph(
    const short* __restrict__ A, const short* __restrict__ Bw,
    const float* __restrict__ bias, unsigned short* __restrict__ Cout) {
    constexpr int NT = K / 64;
    constexpr unsigned OFF_A0 = 0, OFF_B0 = 16384, OFF_A1 = 32768, OFF_B1 = 49152;
    __shared__ __align__(16) short smem[65536];   // 128 KB

    const int tid = threadIdx.x;
    const int lane = tid & 63;
    const int wave = tid >> 6;      // 0..7
    const int wm = wave >> 2;       // 0..1  -> 128-row half
    const int wn = wave & 3;        // 0..3  -> 64-col quarter
    const int l15 = lane & 15;
    const int quad = lane >> 4;
    const int srow = lane >> 3;
    const int skb8 = ((lane & 7) ^ srow) << 3;

    // bijective XCD swizzle
    const int id = blockIdx.x, nwg = gridDim.x;
    const int xcd = id & 7, lid = id >> 3;
    const int q = nwg >> 3, r = nwg & 7;
    const int wgid = (xcd < r ? xcd * (q + 1) : r * (q + 1) + (xcd - r) * q) + lid;
    const int mt = wgid >> 2, nt = wgid & 3;    // 4 n-tiles (N=1024)
    const size_t Abase = (size_t)(mt * 256) * K;
    const size_t Bbase = (size_t)(nt * 256) * K;

    f32x4 acc[8][4];
#pragma unroll
    for (int m = 0; m < 8; ++m)
#pragma unroll
        for (int n = 0; n < 4; ++n) acc[m][n] = f32x4{0.f, 0.f, 0.f, 0.f};

    bf16x8 af[2][2] = {};     // zero-init: slot0's MFMA adds 0
    bf16x8 bfr[4][2] = {};

    auto stage2 = [&](unsigned off, const short* g, size_t rowbase, int kc, int c0, int c1) {
        gl2lds16(g + rowbase + (size_t)(c0 * 8 + srow) * K + kc + skb8, smem + off + c0 * 512);
        gl2lds16(g + rowbase + (size_t)(c1 * 8 + srow) * K + kc + skb8, smem + off + c1 * 512);
    };
    auto stageU = [&](int u, unsigned aOff, unsigned bOff, int kc) {
        if (u == 0)      stage2(bOff, Bw, Bbase, kc, wave * 2, wave * 2 + 1);
        else if (u == 1) stage2(bOff, Bw, Bbase, kc, 16 + wave * 2, 17 + wave * 2);
        else if (u == 2) stage2(aOff, A, Abase, kc, wave, 16 + wave);
        else             stage2(aOff, A, Abase, kc, 8 + wave, 24 + wave);
    };

    // per-lane constant pieces of the swizzled fragment offsets (in shorts)
    const unsigned x0 = (unsigned)((quad ^ (l15 & 7)) << 3);          // kk=0
    const unsigned x1 = (unsigned)(((4 + quad) ^ (l15 & 7)) << 3);    // kk=1

    auto mfma8 = [&](int pprev) {
        __builtin_amdgcn_s_setprio(1);
#pragma unroll
        for (int kk = 0; kk < 2; ++kk)
#pragma unroll
            for (int mm = 0; mm < 2; ++mm)
#pragma unroll
                for (int n = 0; n < 4; ++n)
                    acc[pprev * 2 + mm][n] = __builtin_amdgcn_mfma_f32_16x16x32_bf16(
                        af[mm][kk], bfr[n][kk], acc[pprev * 2 + mm][n], 0, 0, 0);
        __builtin_amdgcn_s_setprio(0);
    };

    auto slot = [&](int ph, int w, unsigned caOff, unsigned cbOff,
                    unsigned naOff, unsigned nbOff) {
        if (ph & 1) {
            if (w < NT - 2) asm volatile("s_waitcnt vmcnt(6)" ::: "memory");
            else            asm volatile("s_waitcnt vmcnt(0)" ::: "memory");
        }
        __builtin_amdgcn_sched_barrier(0);
        __builtin_amdgcn_s_barrier();
        __builtin_amdgcn_sched_barrier(0);
        if (ph == 0) { if (w + 1 < NT) stageU(3, naOff, nbOff, (w + 1) << 6); }
        else         { if (w + 2 < NT) stageU(ph - 1, caOff, cbOff, (w + 2) << 6); }
        __builtin_amdgcn_sched_barrier(0);
        asm volatile("s_waitcnt lgkmcnt(0)" ::: "memory");
        __builtin_amdgcn_sched_barrier(0);
        mfma8((ph + 3) & 3);
        __builtin_amdgcn_sched_barrier(0);
        const short* aA = smem + caOff + ((wm << 7) + l15) * 64;
        const short* aB = smem + cbOff + ((wn << 6) + l15) * 64;
        if (ph == 0) {
#pragma unroll
            for (int n = 0; n < 4; ++n) {
                bfr[n][0] = ds_read_b128_asm(aB + n * 1024 + x0);
                bfr[n][1] = ds_read_b128_asm(aB + n * 1024 + x1);
            }
        }
#pragma unroll
        for (int mm = 0; mm < 2; ++mm) {
            af[mm][0] = ds_read_b128_asm(aA + (ph * 2 + mm) * 1024 + x0);
            af[mm][1] = ds_read_b128_asm(aA + (ph * 2 + mm) * 1024 + x1);
        }
        __builtin_amdgcn_sched_barrier(0);
    };

    // ---- prologue: tile0 complete -> buf0; tile1 U0..U2 -> buf1; no barrier
    stageU(0, OFF_A0, OFF_B0, 0);
    stageU(1, OFF_A0, OFF_B0, 0);
    stageU(2, OFF_A0, OFF_B0, 0);
    stageU(3, OFF_A0, OFF_B0, 0);
    stageU(0, OFF_A1, OFF_B1, 64);
    stageU(1, OFF_A1, OFF_B1, 64);
    stageU(2, OFF_A1, OFF_B1, 64);
    asm volatile("s_waitcnt vmcnt(6)" ::: "memory");

#pragma unroll 1
    for (int w = 0; w < NT; w += 2) {
#pragma unroll
        for (int ph = 0; ph < 4; ++ph)
            slot(ph, w, OFF_A0, OFF_B0, OFF_A1, OFF_B1);
#pragma unroll
        for (int ph = 0; ph < 4; ++ph)
            slot(ph, w + 1, OFF_A1, OFF_B1, OFF_A0, OFF_B0);
    }
    // final MFMA (ph3 of window NT-1; frags read in the last slot)
    asm volatile("s_waitcnt lgkmcnt(0)" ::: "memory");
    __builtin_amdgcn_sched_barrier(0);
    mfma8(3);

    // ---- epilogue: bias+relu -> LDS bf16 (swizzled) -> coalesced store
    __syncthreads();
    unsigned short* cs = (unsigned short*)smem;
#pragma unroll
    for (int n = 0; n < 4; ++n) {
        int colblk = wn * 4 + n;                    // 32B block index 0..15
        int col = (colblk << 4) + l15;
        float bb = bias[nt * 256 + col];
#pragma unroll
        for (int m = 0; m < 8; ++m) {
            int row = (wm << 7) + m * 16 + (quad << 2);
#pragma unroll
            for (int rr = 0; rr < 4; ++rr) {
                int rw = row + rr;
                int sb = colblk ^ ((rw >> 2) & 3);  // bank-group swizzle
                cs[rw * 256 + (sb << 4) + l15] = f2bf(fmaxf(acc[m][n][rr] + bb, 0.f));
            }
        }
    }
    __syncthreads();
    const size_t cbase = (size_t)(mt * 256) * 1024 + nt * 256;
    const int rloc = tid >> 5, cchunk = tid & 31;
#pragma unroll
    for (int rnd = 0; rnd < 16; ++rnd) {
        int rw = rnd * 16 + rloc;
        int blk = cchunk >> 1, half = cchunk & 1;
        int sb = blk ^ ((rw >> 2) & 3);
        short8 v = *(const short8*)&cs[rw * 256 + (sb << 4) + half * 8];
        *(short8*)((unsigned short*)Cout + cbase + (size_t)rw * 1024 + cchunk * 8) = v;
    }
}

// GEMM3 + finalize. Block = 64 rows x 256 cols (full P row-slab), 4 waves.
__global__ __launch_bounds__(256) void gemm3_final(
    const short* __restrict__ H2, const short* __restrict__ W3T,
    const float* __restrict__ b3, const float* __restrict__ x,
    float* __restrict__ out, float* __restrict__ logdet) {
    constexpr int BK = 64, K = 1024;
    __shared__ __align__(16) char raw[40960];
    __shared__ float rowsum[64];
    short* As = (short*)raw;
    short* Bs = (short*)(raw + 8192);
    float* Tbuf = (float*)raw;
    const int tid = threadIdx.x;
    const int lane = tid & 63;
    const int wave = tid >> 6;
    const int tm = blockIdx.x * 64;
    const int srow = lane >> 3;
    const int skb = (lane & 7) ^ srow;
    const int l15 = lane & 15;
    const int quad = lane >> 4;

    if (tid < 64) rowsum[tid] = 0.f;

    f32x4 acc[4][4];
#pragma unroll
    for (int i = 0; i < 4; ++i)
#pragma unroll
        for (int j = 0; j < 4; ++j) acc[i][j] = f32x4{0.f, 0.f, 0.f, 0.f};

    for (int kc = 0; kc < K; kc += BK) {
        __syncthreads();
#pragma unroll
        for (int i = 0; i < 10; ++i) {       // 40 chunks: 8 A + 32 B
            int c = wave * 10 + i;
            if (c < 8) {
                int row = c * 8 + srow;
                gl2lds16(H2 + (size_t)(tm + row) * K + kc + skb * 8, &As[c * 512]);
            } else {
                int row = (c - 8) * 8 + srow;
                gl2lds16(W3T + (size_t)row * K + kc + skb * 8, &Bs[(c - 8) * 512]);
            }
        }
        __syncthreads();
#pragma unroll
        for (int kk = 0; kk < 2; ++kk) {
            int kb = kk * 4 + quad;
            bf16x8 af[4], bfr[4];
#pragma unroll
            for (int mt = 0; mt < 4; ++mt) {
                int r = mt * 16 + l15;
                af[mt] = *(const bf16x8*)&As[r * BK + ((kb ^ (r & 7)) << 3)];
            }
#pragma unroll
            for (int nt = 0; nt < 4; ++nt) {
                int n = wave * 64 + nt * 16 + l15;
                bfr[nt] = *(const bf16x8*)&Bs[n * BK + ((kb ^ (n & 7)) << 3)];
            }
#pragma unroll
            for (int mt = 0; mt < 4; ++mt)
#pragma unroll
                for (int nt = 0; nt < 4; ++nt)
                    acc[mt][nt] = __builtin_amdgcn_mfma_f32_16x16x32_bf16(
                        af[mt], bfr[nt], acc[mt][nt], 0, 0, 0);
        }
    }

    __syncthreads();
    if (wave >= 2) {
#pragma unroll
        for (int nt = 0; nt < 4; ++nt) {
            int col = wave * 64 + nt * 16 + l15;   // 128..255
            float bb = b3[col];
            int cl = col - 128;
#pragma unroll
            for (int mt = 0; mt < 4; ++mt) {
#pragma unroll
                for (int rr = 0; rr < 4; ++rr) {
                    int m = mt * 16 + quad * 4 + rr;
                    Tbuf[m * 132 + cl] = acc[mt][nt][rr] + bb;
                }
            }
        }
    }
    __syncthreads();
    if (wave < 2) {
#pragma unroll
        for (int mt = 0; mt < 4; ++mt) {
#pragma unroll
            for (int rr = 0; rr < 4; ++rr) {
                int m = mt * 16 + quad * 4 + rr;
                int grow = tm + m;
                float s = 0.f;
#pragma unroll
                for (int nt = 0; nt < 4; ++nt) {
                    int j = wave * 64 + nt * 16 + l15;   // 0..127
                    float p = acc[mt][nt][rr] + b3[j];
                    p = fminf(fmaxf(p, -15.f), 15.f);
                    float e2 = __expf(2.f * p);
                    float ls = (e2 - 1.f) / (e2 + 1.f);  // tanh(p)
                    s += ls;
                    float tt = Tbuf[m * 132 + j];
                    float2 xv = *(const float2*)&x[(size_t)grow * 256 + 2 * j];
                    float2 ov;
                    ov.x = xv.x;
                    ov.y = xv.y * __expf(ls) + tt;
                    *(float2*)&out[(size_t)grow * 256 + 2 * j] = ov;
                }
                s += __shfl_xor(s, 1);
                s += __shfl_xor(s, 2);
                s += __shfl_xor(s, 4);
                s += __shfl_xor(s, 8);
                if (l15 == 0) atomicAdd(&rowsum[m], s);
            }
        }
    }
    __syncthreads();
    if (tid < 64) logdet[tm + tid] = rowsum[tid];
}

extern "C" void kernel_launch(void* const* d_in, const int* in_sizes, int n_in,
                              void* d_out, int out_size, void* d_ws, size_t ws_size,
                              hipStream_t stream) {
    const float* x = (const float*)d_in[0];
    const float* cond = (const float*)d_in[1];
    const float* W1 = (const float*)d_in[2];
    const float* b1 = (const float*)d_in[3];
    const float* W2 = (const float*)d_in[4];
    const float* b2 = (const float*)d_in[5];
    const float* Wsp = (const float*)d_in[6];
    const float* bs = (const float*)d_in[7];
    const float* Wtp = (const float*)d_in[8];
    const float* bt = (const float*)d_in[9];

    char* ws = (char*)d_ws;
    short* W1T = (short*)(ws);                          // 1024x256 bf16 = 512 KB
    short* W2T = (short*)(ws + 524288ull);              // 1024x1024 bf16 = 2 MB
    short* W3T = (short*)(ws + 2621440ull);             // 256x1024 bf16 = 512 KB
    float* b3  = (float*)(ws + 3145728ull);             // 1 KB
    short* Aprep = (short*)(ws + 3149824ull);           // 65536x256 bf16 = 32 MB
    const size_t chunk_base = 3149824ull + 33554432ull;

    // Per-chunk scratch: H1 = 2048*R, H2 = 2048*R.
    int n_chunks = 1;
    while (n_chunks < 512) {
        size_t rp = (size_t)B_ROWS / n_chunks;
        if (chunk_base + rp * 4096ull <= ws_size) break;
        n_chunks *= 2;
    }
    const size_t RP = (size_t)B_ROWS / n_chunks;

    float* out = (float*)d_out;
    float* logdet = out + (size_t)B_ROWS * D_DIM;

    transpose_bf16<<<(32768 + 255) / 256, 256, 0, stream>>>(W1, W1T, 256, 1024, 32768);
    transpose_bf16<<<(131072 + 255) / 256, 256, 0, stream>>>(W2, W2T, 1024, 1024, 131072);
    transpose_bf16<<<(16384 + 255) / 256, 256, 0, stream>>>(Wsp, W3T, 1024, 128, 16384);
    transpose_bf16<<<(16384 + 255) / 256, 256, 0, stream>>>(Wtp, W3T + 131072, 1024, 128, 16384);
    prep_b3<<<1, 256, 0, stream>>>(bs, bt, b3);
    prep_a<<<B_ROWS * 32 / 256, 256, 0, stream>>>(x, cond, Aprep);

    for (int c = 0; c < n_chunks; ++c) {
        const size_t r0 = (size_t)c * RP;
        short* H1 = (short*)(ws + chunk_base);
        short* H2 = (short*)(ws + chunk_base + 2048ull * RP);
        const int mtiles = (int)(RP / 128);

        if ((RP & 255) == 0) {
            gemm2_8ph<256><<<(int)(RP / 256) * 4, 512, 0, stream>>>(
                Aprep + r0 * 256, W1T, b1, (unsigned short*)H1);
            gemm2_8ph<1024><<<(int)(RP / 256) * 4, 512, 0, stream>>>(
                H1, W2T, b2, (unsigned short*)H2);
        } else {
            gemm_tn<<<mtiles * 8, 256, 0, stream>>>(
                Aprep + r0 * 256, W1T, b1, (unsigned short*)H1, mtiles, H_DIM, 256);
            gemm_tn<<<mtiles * 8, 256, 0, stream>>>(
                H1, W2T, b2, (unsigned short*)H2, mtiles, H_DIM, H_DIM);
        }
        gemm3_final<<<(int)(RP / 64), 256, 0, stream>>>(
            H2, W3T, b3, x + r0 * D_DIM, out + r0 * D_DIM, logdet + r0);
    }
}

// Round 7
// 427.303 us; speedup vs baseline: 1.1894x; 1.0731x over previous
//
#include <hip/hip_runtime.h>
#include <hip/hip_bf16.h>
#include <math.h>

#define B_ROWS 65536
#define D_DIM 256
#define C_DIM 128
#define H_DIM 1024

typedef __bf16 bf16x8 __attribute__((ext_vector_type(8)));
typedef float f32x4 __attribute__((ext_vector_type(4)));
typedef short short8 __attribute__((ext_vector_type(8)));

__device__ __forceinline__ unsigned short f2bf(float f) {
    unsigned int u = __float_as_uint(f);
    u += 0x7fffu + ((u >> 16) & 1u);
    return (unsigned short)(u >> 16);
}

__device__ __forceinline__ void gl2lds16(const void* g, void* l) {
    __builtin_amdgcn_global_load_lds(
        (const __attribute__((address_space(1))) unsigned int*)g,
        (__attribute__((address_space(3))) unsigned int*)l, 16, 0, 0);
}

// Opaque LDS read via a proper address_space(3) pointer. Compiler cannot see
// the dependency on outstanding global_load_lds -> no conservative vmcnt(0)
// drains; correctness comes from explicit barriers + counted vmcnt.
__device__ __forceinline__ bf16x8 ds_read_b128_asm(const short* p) {
    bf16x8 r;
    asm volatile("ds_read_b128 %0, %1"
                 : "=v"(r)
                 : "v"((const __attribute__((address_space(3))) short*)p));
    return r;
}

// XCD-aware swizzle helpers
__device__ __forceinline__ int xcd_swz(int id, int nwg) {
    int xcd = id & 7, lid = id >> 3;
    int q = nwg >> 3, r = nwg & 7;
    return (xcd < r ? xcd * (q + 1) : r * (q + 1) + (xcd - r) * q) + lid;
}

__device__ __forceinline__ void swizzle_mn(int id, int mtiles, int& m, int& n) {
    if ((mtiles & 7) == 0) {
        int g = id >> 6, r = id & 63;
        m = g * 8 + (r & 7);
        n = r >> 3;
    } else {
        m = id >> 3;
        n = id & 7;
    }
}

// ===========================================================================
// Merged prep: 4 weight transposes + b3 concat + A-prep, one launch.
// Flat-tid range dispatch; all segments memory-bound.
//   [0,32768)        W1 (256x1024)  -> W1T (1024x256)
//   [32768,163840)   W2 (1024x1024) -> W2T (1024x1024)
//   [163840,180224)  Ws (1024x128)  -> W3T rows 0-127
//   [180224,196608)  Wt (1024x128)  -> W3T rows 128-255
//   [196608,196864)  b3 = [bs|bt]
//   [196864,...)     A[m] = [bf16(x[m,even]) | bf16(cond[m])]
// ===========================================================================
__global__ __launch_bounds__(256) void prep_all(
    const float* __restrict__ W1, const float* __restrict__ W2,
    const float* __restrict__ Ws, const float* __restrict__ Wt,
    const float* __restrict__ bs, const float* __restrict__ bt,
    const float* __restrict__ x, const float* __restrict__ cond,
    short* __restrict__ W1T, short* __restrict__ W2T, short* __restrict__ W3T,
    float* __restrict__ b3, short* __restrict__ A) {
    int t = blockIdx.x * 256 + threadIdx.x;
    if (t < 196864) {
        short8 o;
        if (t < 32768) {
            int n = t >> 5, k0 = (t & 31) << 3;
#pragma unroll
            for (int j = 0; j < 8; ++j) o[j] = (short)f2bf(W1[(size_t)(k0 + j) * 1024 + n]);
            *(short8*)&W1T[(size_t)n * 256 + k0] = o;
        } else if (t < 163840) {
            int u = t - 32768;
            int n = u >> 7, k0 = (u & 127) << 3;
#pragma unroll
            for (int j = 0; j < 8; ++j) o[j] = (short)f2bf(W2[(size_t)(k0 + j) * 1024 + n]);
            *(short8*)&W2T[(size_t)n * 1024 + k0] = o;
        } else if (t < 180224) {
            int u = t - 163840;
            int n = u >> 7, k0 = (u & 127) << 3;
#pragma unroll
            for (int j = 0; j < 8; ++j) o[j] = (short)f2bf(Ws[(size_t)(k0 + j) * 128 + n]);
            *(short8*)&W3T[(size_t)n * 1024 + k0] = o;
        } else if (t < 196608) {
            int u = t - 180224;
            int n = u >> 7, k0 = (u & 127) << 3;
#pragma unroll
            for (int j = 0; j < 8; ++j) o[j] = (short)f2bf(Wt[(size_t)(k0 + j) * 128 + n]);
            *(short8*)&W3T[131072 + (size_t)n * 1024 + k0] = o;
        } else {
            int i = t - 196608;
            b3[i] = (i < 128) ? bs[i] : bt[i - 128];
        }
    } else {
        int u = t - 196864;
        int m = u >> 5, seg = u & 31;
        short8 o;
        if (seg < 16) {
            const float4* p = (const float4*)(x + (size_t)m * 256 + seg * 16);
            float4 a = p[0], b = p[1], c = p[2], d = p[3];
            o[0] = (short)f2bf(a.x); o[1] = (short)f2bf(a.z);
            o[2] = (short)f2bf(b.x); o[3] = (short)f2bf(b.z);
            o[4] = (short)f2bf(c.x); o[5] = (short)f2bf(c.z);
            o[6] = (short)f2bf(d.x); o[7] = (short)f2bf(d.z);
        } else {
            const float4* p = (const float4*)(cond + (size_t)m * 128 + (seg - 16) * 8);
            float4 a = p[0], b = p[1];
            o[0] = (short)f2bf(a.x); o[1] = (short)f2bf(a.y);
            o[2] = (short)f2bf(a.z); o[3] = (short)f2bf(a.w);
            o[4] = (short)f2bf(b.x); o[5] = (short)f2bf(b.y);
            o[6] = (short)f2bf(b.z); o[7] = (short)f2bf(b.w);
        }
        *(short8*)&A[(size_t)m * 256 + seg * 8] = o;
    }
}

// Generic fallback GEMM (128x128 tile), used only if RP % 256 != 0.
__global__ __launch_bounds__(256) void gemm_tn(
    const short* __restrict__ A, const short* __restrict__ Bw,
    const float* __restrict__ bias, unsigned short* __restrict__ Cout,
    int mtiles, int N, int K) {
    constexpr int BK = 64;
    __shared__ __align__(16) short As[128 * BK];
    __shared__ __align__(16) short Bs[128 * BK];
    const int tid = threadIdx.x;
    const int lane = tid & 63;
    const int wave = tid >> 6;
    int mt, nt;
    swizzle_mn(blockIdx.x, mtiles, mt, nt);
    const int tm = mt * 128, tn = nt * 128;
    const int mo = (wave >> 1) * 64;
    const int no = (wave & 1) * 64;

    f32x4 acc[4][4];
#pragma unroll
    for (int i = 0; i < 4; ++i)
#pragma unroll
        for (int j = 0; j < 4; ++j) acc[i][j] = f32x4{0.f, 0.f, 0.f, 0.f};

    const int srow = lane >> 3;
    const int skb = (lane & 7) ^ srow;

    for (int kc = 0; kc < K; kc += BK) {
        __syncthreads();
#pragma unroll
        for (int i = 0; i < 4; ++i) {
            int c = wave * 4 + i;
            int row = c * 8 + srow;
            gl2lds16(A + (size_t)(tm + row) * K + kc + skb * 8, &As[c * 512]);
            gl2lds16(Bw + (size_t)(tn + row) * K + kc + skb * 8, &Bs[c * 512]);
        }
        __syncthreads();
#pragma unroll
        for (int kk = 0; kk < 2; ++kk) {
            bf16x8 af[4], bfr[4];
            int kb = kk * 4 + (lane >> 4);
#pragma unroll
            for (int t = 0; t < 4; ++t) {
                int r = mo + t * 16 + (lane & 15);
                af[t] = *(const bf16x8*)&As[r * BK + ((kb ^ (r & 7)) << 3)];
                int n = no + t * 16 + (lane & 15);
                bfr[t] = *(const bf16x8*)&Bs[n * BK + ((kb ^ (n & 7)) << 3)];
            }
#pragma unroll
            for (int i = 0; i < 4; ++i)
#pragma unroll
                for (int j = 0; j < 4; ++j)
                    acc[i][j] = __builtin_amdgcn_mfma_f32_16x16x32_bf16(
                        af[i], bfr[j], acc[i][j], 0, 0, 0);
        }
    }

#pragma unroll
    for (int j = 0; j < 4; ++j) {
        int col = tn + no + j * 16 + (lane & 15);
        float bb = bias[col];
#pragma unroll
        for (int i = 0; i < 4; ++i) {
            int row0 = tm + mo + i * 16 + ((lane >> 4) << 2);
            f32x4 v = acc[i][j];
#pragma unroll
            for (int rr = 0; rr < 4; ++rr)
                Cout[(size_t)(row0 + rr) * N + col] = f2bf(fmaxf(v[rr] + bb, 0.f));
        }
    }
}

// ===========================================================================
// Pipelined GEMM (templated K), 256x256 tile, BK=64, 8 waves (2M x 4N).
// Slot-pipelined: [vmcnt? -> BARRIER -> stage -> lgkmcnt(0) -> MFMA(frags
// read last slot) -> ds_read(frags for next slot)]. See round-6 ledger.
// ===========================================================================
template<int K>
__global__ __launch_bounds__(512, 2) void gemm2_8ph(
    const short* __restrict__ A, const short* __restrict__ Bw,
    const float* __restrict__ bias, unsigned short* __restrict__ Cout) {
    constexpr int NT = K / 64;
    constexpr unsigned OFF_A0 = 0, OFF_B0 = 16384, OFF_A1 = 32768, OFF_B1 = 49152;
    __shared__ __align__(16) short smem[65536];   // 128 KB

    const int tid = threadIdx.x;
    const int lane = tid & 63;
    const int wave = tid >> 6;      // 0..7
    const int wm = wave >> 2;       // 0..1  -> 128-row half
    const int wn = wave & 3;        // 0..3  -> 64-col quarter
    const int l15 = lane & 15;
    const int quad = lane >> 4;
    const int srow = lane >> 3;
    const int skb8 = ((lane & 7) ^ srow) << 3;

    const int wgid = xcd_swz(blockIdx.x, gridDim.x);
    const int mt = wgid >> 2, nt = wgid & 3;    // 4 n-tiles (N=1024)
    const size_t Abase = (size_t)(mt * 256) * K;
    const size_t Bbase = (size_t)(nt * 256) * K;

    f32x4 acc[8][4];
#pragma unroll
    for (int m = 0; m < 8; ++m)
#pragma unroll
        for (int n = 0; n < 4; ++n) acc[m][n] = f32x4{0.f, 0.f, 0.f, 0.f};

    bf16x8 af[2][2] = {};     // zero-init: slot0's MFMA adds 0
    bf16x8 bfr[4][2] = {};

    auto stage2 = [&](unsigned off, const short* g, size_t rowbase, int kc, int c0, int c1) {
        gl2lds16(g + rowbase + (size_t)(c0 * 8 + srow) * K + kc + skb8, smem + off + c0 * 512);
        gl2lds16(g + rowbase + (size_t)(c1 * 8 + srow) * K + kc + skb8, smem + off + c1 * 512);
    };
    auto stageU = [&](int u, unsigned aOff, unsigned bOff, int kc) {
        if (u == 0)      stage2(bOff, Bw, Bbase, kc, wave * 2, wave * 2 + 1);
        else if (u == 1) stage2(bOff, Bw, Bbase, kc, 16 + wave * 2, 17 + wave * 2);
        else if (u == 2) stage2(aOff, A, Abase, kc, wave, 16 + wave);
        else             stage2(aOff, A, Abase, kc, 8 + wave, 24 + wave);
    };

    const unsigned x0 = (unsigned)((quad ^ (l15 & 7)) << 3);          // kk=0
    const unsigned x1 = (unsigned)(((4 + quad) ^ (l15 & 7)) << 3);    // kk=1

    auto mfma8 = [&](int pprev) {
        __builtin_amdgcn_s_setprio(1);
#pragma unroll
        for (int kk = 0; kk < 2; ++kk)
#pragma unroll
            for (int mm = 0; mm < 2; ++mm)
#pragma unroll
                for (int n = 0; n < 4; ++n)
                    acc[pprev * 2 + mm][n] = __builtin_amdgcn_mfma_f32_16x16x32_bf16(
                        af[mm][kk], bfr[n][kk], acc[pprev * 2 + mm][n], 0, 0, 0);
        __builtin_amdgcn_s_setprio(0);
    };

    auto slot = [&](int ph, int w, unsigned caOff, unsigned cbOff,
                    unsigned naOff, unsigned nbOff) {
        if (ph & 1) {
            if (w < NT - 2) asm volatile("s_waitcnt vmcnt(6)" ::: "memory");
            else            asm volatile("s_waitcnt vmcnt(0)" ::: "memory");
        }
        __builtin_amdgcn_sched_barrier(0);
        __builtin_amdgcn_s_barrier();
        __builtin_amdgcn_sched_barrier(0);
        if (ph == 0) { if (w + 1 < NT) stageU(3, naOff, nbOff, (w + 1) << 6); }
        else         { if (w + 2 < NT) stageU(ph - 1, caOff, cbOff, (w + 2) << 6); }
        __builtin_amdgcn_sched_barrier(0);
        asm volatile("s_waitcnt lgkmcnt(0)" ::: "memory");
        __builtin_amdgcn_sched_barrier(0);
        mfma8((ph + 3) & 3);
        __builtin_amdgcn_sched_barrier(0);
        const short* aA = smem + caOff + ((wm << 7) + l15) * 64;
        const short* aB = smem + cbOff + ((wn << 6) + l15) * 64;
        if (ph == 0) {
#pragma unroll
            for (int n = 0; n < 4; ++n) {
                bfr[n][0] = ds_read_b128_asm(aB + n * 1024 + x0);
                bfr[n][1] = ds_read_b128_asm(aB + n * 1024 + x1);
            }
        }
#pragma unroll
        for (int mm = 0; mm < 2; ++mm) {
            af[mm][0] = ds_read_b128_asm(aA + (ph * 2 + mm) * 1024 + x0);
            af[mm][1] = ds_read_b128_asm(aA + (ph * 2 + mm) * 1024 + x1);
        }
        __builtin_amdgcn_sched_barrier(0);
    };

    stageU(0, OFF_A0, OFF_B0, 0);
    stageU(1, OFF_A0, OFF_B0, 0);
    stageU(2, OFF_A0, OFF_B0, 0);
    stageU(3, OFF_A0, OFF_B0, 0);
    stageU(0, OFF_A1, OFF_B1, 64);
    stageU(1, OFF_A1, OFF_B1, 64);
    stageU(2, OFF_A1, OFF_B1, 64);
    asm volatile("s_waitcnt vmcnt(6)" ::: "memory");

#pragma unroll 1
    for (int w = 0; w < NT; w += 2) {
#pragma unroll
        for (int ph = 0; ph < 4; ++ph)
            slot(ph, w, OFF_A0, OFF_B0, OFF_A1, OFF_B1);
#pragma unroll
        for (int ph = 0; ph < 4; ++ph)
            slot(ph, w + 1, OFF_A1, OFF_B1, OFF_A0, OFF_B0);
    }
    asm volatile("s_waitcnt lgkmcnt(0)" ::: "memory");
    __builtin_amdgcn_sched_barrier(0);
    mfma8(3);

    // ---- epilogue: bias+relu -> LDS bf16 (swizzled) -> coalesced store
    __syncthreads();
    unsigned short* cs = (unsigned short*)smem;
#pragma unroll
    for (int n = 0; n < 4; ++n) {
        int colblk = wn * 4 + n;
        int col = (colblk << 4) + l15;
        float bb = bias[nt * 256 + col];
#pragma unroll
        for (int m = 0; m < 8; ++m) {
            int row = (wm << 7) + m * 16 + (quad << 2);
#pragma unroll
            for (int rr = 0; rr < 4; ++rr) {
                int rw = row + rr;
                int sb = colblk ^ ((rw >> 2) & 3);
                cs[rw * 256 + (sb << 4) + l15] = f2bf(fmaxf(acc[m][n][rr] + bb, 0.f));
            }
        }
    }
    __syncthreads();
    const size_t cbase = (size_t)(mt * 256) * 1024 + nt * 256;
    const int rloc = tid >> 5, cchunk = tid & 31;
#pragma unroll
    for (int rnd = 0; rnd < 16; ++rnd) {
        int rw = rnd * 16 + rloc;
        int blk = cchunk >> 1, half = cchunk & 1;
        int sb = blk ^ ((rw >> 2) & 3);
        short8 v = *(const short8*)&cs[rw * 256 + (sb << 4) + half * 8];
        *(short8*)((unsigned short*)Cout + cbase + (size_t)rw * 1024 + cchunk * 8) = v;
    }
}

// ===========================================================================
// GEMM3 + finalize, slot-pipelined. Block = 128 rows x 256 cols (full P
// row-slab), 8 waves (2M x 4N), per-wave 64x64 (acc[4][4]).
// LDS: A(128x64)+B(256x64) double-buffered = 96 KB; Tbuf overlays after.
// Stage units (16 chunks = 2 loads/thread): UA = A rows 0-127,
// UB1 = B rows 0-127, UB2 = B rows 128-255.
// Slot schedule: ph0 -> UA(w+1) into OTHER buf (its A last read at
// (w-1,ph3), pre-barrier); ph1 -> UB1(w+2) into cur (B read at (w,ph0));
// ph2 -> UB2(w+2) into cur; ph3 -> none.
// vmcnt(4) before EVERY barrier: stages S(3w)=UA(w+1)@ph0, S(3w+1)=UB1(w+2)
// @ph1, S(3w+2)=UB2(w+2)@ph2. Drain keeps 2 newest units: UA(w+1) drains at
// (w,ph3) < first read (w+1,ph0); UB1/UB2(w+2) drain at (w+1,ph1)/(w+1,ph2)
// < reads (w+2,ph0). Prologue: UA(0),UB1(0),UB2(0),UB1(1),UB2(1), vmcnt(4).
// Tail w>=NT-2: vmcnt(0), stage guards off.
// Finalize: t-waves (wn>=2) deposit t+bt into Tbuf; s-waves (wn<2) compute
// tanh, out, and logdet rowsum (16-lane shfl + LDS atomic).
// ===========================================================================
__global__ __launch_bounds__(512, 2) void gemm3_pipe(
    const short* __restrict__ H2, const short* __restrict__ W3T,
    const float* __restrict__ b3, const float* __restrict__ x,
    float* __restrict__ out, float* __restrict__ logdet) {
    constexpr int K = 1024, NT = 16;
    constexpr unsigned OFF_A0 = 0, OFF_B0 = 8192, OFF_A1 = 24576, OFF_B1 = 32768;
    __shared__ __align__(16) short smem[49152];   // 96 KB
    __shared__ float rowsum[128];

    const int tid = threadIdx.x;
    const int lane = tid & 63;
    const int wave = tid >> 6;      // 0..7
    const int wm = wave >> 2;       // 0..1  -> 64-row half
    const int wn = wave & 3;        // 0..3  -> 64-col quarter
    const int l15 = lane & 15;
    const int quad = lane >> 4;
    const int srow = lane >> 3;
    const int skb8 = ((lane & 7) ^ srow) << 3;

    const int mt = xcd_swz(blockIdx.x, gridDim.x);
    const int tm = mt * 128;
    const size_t Abase = (size_t)tm * K;

    if (tid < 128) rowsum[tid] = 0.f;

    f32x4 acc[4][4];
#pragma unroll
    for (int i = 0; i < 4; ++i)
#pragma unroll
        for (int j = 0; j < 4; ++j) acc[i][j] = f32x4{0.f, 0.f, 0.f, 0.f};

    bf16x8 af[2] = {};        // zero-init: slot0's MFMA adds 0
    bf16x8 bfr[4][2] = {};

    auto stage2 = [&](unsigned off, const short* g, size_t rowbase, int kc, int c0, int c1) {
        gl2lds16(g + rowbase + (size_t)(c0 * 8 + srow) * K + kc + skb8, smem + off + c0 * 512);
        gl2lds16(g + rowbase + (size_t)(c1 * 8 + srow) * K + kc + skb8, smem + off + c1 * 512);
    };
    auto stageA  = [&](unsigned aOff, int kc) { stage2(aOff, H2, Abase, kc, wave, 8 + wave); };
    auto stageB1 = [&](unsigned bOff, int kc) { stage2(bOff, W3T, 0, kc, 2 * wave, 2 * wave + 1); };
    auto stageB2 = [&](unsigned bOff, int kc) { stage2(bOff, W3T, 0, kc, 16 + 2 * wave, 17 + 2 * wave); };

    const unsigned x0 = (unsigned)((quad ^ (l15 & 7)) << 3);          // kk=0
    const unsigned x1 = (unsigned)(((4 + quad) ^ (l15 & 7)) << 3);    // kk=1

    auto mfma4 = [&](int pprev) {
        __builtin_amdgcn_s_setprio(1);
#pragma unroll
        for (int kk = 0; kk < 2; ++kk)
#pragma unroll
            for (int n = 0; n < 4; ++n)
                acc[pprev][n] = __builtin_amdgcn_mfma_f32_16x16x32_bf16(
                    af[kk], bfr[n][kk], acc[pprev][n], 0, 0, 0);
        __builtin_amdgcn_s_setprio(0);
    };

    auto slot = [&](int ph, int w, unsigned caOff, unsigned cbOff, unsigned naOff) {
        if (w < NT - 2) asm volatile("s_waitcnt vmcnt(4)" ::: "memory");
        else            asm volatile("s_waitcnt vmcnt(0)" ::: "memory");
        __builtin_amdgcn_sched_barrier(0);
        __builtin_amdgcn_s_barrier();
        __builtin_amdgcn_sched_barrier(0);
        if (ph == 0)      { if (w + 1 < NT) stageA(naOff, (w + 1) << 6); }
        else if (ph == 1) { if (w + 2 < NT) stageB1(cbOff, (w + 2) << 6); }
        else if (ph == 2) { if (w + 2 < NT) stageB2(cbOff, (w + 2) << 6); }
        __builtin_amdgcn_sched_barrier(0);
        asm volatile("s_waitcnt lgkmcnt(0)" ::: "memory");
        __builtin_amdgcn_sched_barrier(0);
        mfma4((ph + 3) & 3);
        __builtin_amdgcn_sched_barrier(0);
        const short* aA = smem + caOff + ((wm << 6) + l15) * 64;
        const short* aB = smem + cbOff + ((wn << 6) + l15) * 64;
        if (ph == 0) {
#pragma unroll
            for (int n = 0; n < 4; ++n) {
                bfr[n][0] = ds_read_b128_asm(aB + n * 1024 + x0);
                bfr[n][1] = ds_read_b128_asm(aB + n * 1024 + x1);
            }
        }
        af[0] = ds_read_b128_asm(aA + ph * 1024 + x0);
        af[1] = ds_read_b128_asm(aA + ph * 1024 + x1);
        __builtin_amdgcn_sched_barrier(0);
    };

    // prologue: window 0 complete -> buf0; B of window 1 -> buf1
    stageA(OFF_A0, 0);
    stageB1(OFF_B0, 0);
    stageB2(OFF_B0, 0);
    stageB1(OFF_B1, 64);
    stageB2(OFF_B1, 64);
    asm volatile("s_waitcnt vmcnt(4)" ::: "memory");

#pragma unroll 1
    for (int w = 0; w < NT; w += 2) {
#pragma unroll
        for (int ph = 0; ph < 4; ++ph)
            slot(ph, w, OFF_A0, OFF_B0, OFF_A1);
#pragma unroll
        for (int ph = 0; ph < 4; ++ph)
            slot(ph, w + 1, OFF_A1, OFF_B1, OFF_A0);
    }
    asm volatile("s_waitcnt lgkmcnt(0)" ::: "memory");
    __builtin_amdgcn_sched_barrier(0);
    mfma4(3);

    // ---- finalize ----
    __syncthreads();
    float* Tbuf = (float*)smem;     // 128 x 132 f32 = 67.6 KB, overlays staging
    if (wn >= 2) {
#pragma unroll
        for (int n = 0; n < 4; ++n) {
            int col = (wn << 6) + n * 16 + l15;   // 128..255
            float bb = b3[col];
            int cl = col - 128;
#pragma unroll
            for (int mm = 0; mm < 4; ++mm) {
#pragma unroll
                for (int rr = 0; rr < 4; ++rr) {
                    int m = (wm << 6) + mm * 16 + quad * 4 + rr;
                    Tbuf[m * 132 + cl] = acc[mm][n][rr] + bb;
                }
            }
        }
    }
    __syncthreads();
    if (wn < 2) {
#pragma unroll
        for (int mm = 0; mm < 4; ++mm) {
#pragma unroll
            for (int rr = 0; rr < 4; ++rr) {
                int m = (wm << 6) + mm * 16 + quad * 4 + rr;
                int grow = tm + m;
                float s = 0.f;
#pragma unroll
                for (int n = 0; n < 4; ++n) {
                    int j = (wn << 6) + n * 16 + l15;   // 0..127
                    float p = acc[mm][n][rr] + b3[j];
                    p = fminf(fmaxf(p, -15.f), 15.f);
                    float e2 = __expf(2.f * p);
                    float ls = (e2 - 1.f) / (e2 + 1.f);  // tanh(p)
                    s += ls;
                    float tt = Tbuf[m * 132 + j];
                    float2 xv = *(const float2*)&x[(size_t)grow * 256 + 2 * j];
                    float2 ov;
                    ov.x = xv.x;
                    ov.y = xv.y * __expf(ls) + tt;
                    *(float2*)&out[(size_t)grow * 256 + 2 * j] = ov;
                }
                s += __shfl_xor(s, 1);
                s += __shfl_xor(s, 2);
                s += __shfl_xor(s, 4);
                s += __shfl_xor(s, 8);
                if (l15 == 0) atomicAdd(&rowsum[m], s);
            }
        }
    }
    __syncthreads();
    if (tid < 128) logdet[tm + tid] = rowsum[tid];
}

extern "C" void kernel_launch(void* const* d_in, const int* in_sizes, int n_in,
                              void* d_out, int out_size, void* d_ws, size_t ws_size,
                              hipStream_t stream) {
    const float* x = (const float*)d_in[0];
    const float* cond = (const float*)d_in[1];
    const float* W1 = (const float*)d_in[2];
    const float* b1 = (const float*)d_in[3];
    const float* W2 = (const float*)d_in[4];
    const float* b2 = (const float*)d_in[5];
    const float* Wsp = (const float*)d_in[6];
    const float* bs = (const float*)d_in[7];
    const float* Wtp = (const float*)d_in[8];
    const float* bt = (const float*)d_in[9];

    char* ws = (char*)d_ws;
    short* W1T = (short*)(ws);                          // 1024x256 bf16 = 512 KB
    short* W2T = (short*)(ws + 524288ull);              // 1024x1024 bf16 = 2 MB
    short* W3T = (short*)(ws + 2621440ull);             // 256x1024 bf16 = 512 KB
    float* b3  = (float*)(ws + 3145728ull);             // 1 KB
    short* Aprep = (short*)(ws + 3149824ull);           // 65536x256 bf16 = 32 MB
    const size_t chunk_base = 3149824ull + 33554432ull;

    int n_chunks = 1;
    while (n_chunks < 512) {
        size_t rp = (size_t)B_ROWS / n_chunks;
        if (chunk_base + rp * 4096ull <= ws_size) break;
        n_chunks *= 2;
    }
    const size_t RP = (size_t)B_ROWS / n_chunks;

    float* out = (float*)d_out;
    float* logdet = out + (size_t)B_ROWS * D_DIM;

    prep_all<<<(196864 + B_ROWS * 32 + 255) / 256, 256, 0, stream>>>(
        W1, W2, Wsp, Wtp, bs, bt, x, cond, W1T, W2T, W3T, b3, Aprep);

    for (int c = 0; c < n_chunks; ++c) {
        const size_t r0 = (size_t)c * RP;
        short* H1 = (short*)(ws + chunk_base);
        short* H2 = (short*)(ws + chunk_base + 2048ull * RP);
        const int mtiles = (int)(RP / 128);

        if ((RP & 255) == 0) {
            gemm2_8ph<256><<<(int)(RP / 256) * 4, 512, 0, stream>>>(
                Aprep + r0 * 256, W1T, b1, (unsigned short*)H1);
            gemm2_8ph<1024><<<(int)(RP / 256) * 4, 512, 0, stream>>>(
                H1, W2T, b2, (unsigned short*)H2);
        } else {
            gemm_tn<<<mtiles * 8, 256, 0, stream>>>(
                Aprep + r0 * 256, W1T, b1, (unsigned short*)H1, mtiles, H_DIM, 256);
            gemm_tn<<<mtiles * 8, 256, 0, stream>>>(
                H1, W2T, b2, (unsigned short*)H2, mtiles, H_DIM, H_DIM);
        }
        gemm3_pipe<<<(int)(RP / 128), 512, 0, stream>>>(
            H2, W3T, b3, x + r0 * D_DIM, out + r0 * D_DIM, logdet + r0);
    }
}